// Round 5
// baseline (262.121 us; speedup 1.0000x reference)
//
#include <hip/hip_runtime.h>

typedef unsigned short ushort_t;
typedef __bf16 bf16x8 __attribute__((ext_vector_type(8)));
typedef float f32x4 __attribute__((ext_vector_type(4)));
typedef const __attribute__((address_space(1))) void* gas1_t;
typedef __attribute__((address_space(3))) void* las3_t;

#define BB 2
#define LL 4096
#define DIMM 512
#define TOK (BB*LL)      // 8192
#define NCH 512          // BH*N chunks
#define MAX_LR_C 0.01f
#define EPS_C 1e-6f

__device__ __forceinline__ float sigmoidf_(float x){ return 1.0f/(1.0f + __expf(-x)); }
__device__ __forceinline__ ushort_t f2bf(float f){
    unsigned u = __builtin_bit_cast(unsigned, f);
    unsigned r = u + 0x7FFFu + ((u>>16)&1u);
    return (ushort_t)(r>>16);
}
__device__ __forceinline__ float bf2f(ushort_t h){
    unsigned u = ((unsigned)h)<<16; return __builtin_bit_cast(float, u);
}

// swizzled LDS offsets (element units, bf16): <=2-way bank aliasing (free, m136)
__device__ __forceinline__ int sw64x128(int t, int d){
    return (t<<7) | ((((d>>3) ^ (t&15))<<3) | (d&7));
}
__device__ __forceinline__ int sw128x64(int x, int t){
    return (x<<6) | ((((t>>3) ^ (x&7))<<3) | (t&7));
}

// ---------------------------------------------------------------------------
// Weight conversion/transpose to bf16 + d_out empty-prefix fill + zero accums.
// ---------------------------------------------------------------------------
__global__ __launch_bounds__(256) void k_convert(
    const float* __restrict__ w_kv, const float* __restrict__ w_q,
    const float* __restrict__ w_comb, const float* __restrict__ w0,
    const float* __restrict__ w1, const float* __restrict__ empty,
    ushort_t* __restrict__ w_kvT, ushort_t* __restrict__ w_qT,
    ushort_t* __restrict__ w_combT, ushort_t* __restrict__ w0T_b,
    ushort_t* __restrict__ w1T_b, ushort_t* __restrict__ w1row_b,
    float* __restrict__ w0T_f, float* __restrict__ w1T_f,
    float* __restrict__ outp, float* __restrict__ amraw, float* __restrict__ dcraw)
{
    int i = blockIdx.x*256 + threadIdx.x;
    if (i < 524288){ int n=i>>9, k=i&511; w_kvT[i] = f2bf(w_kv[k*1024+n]); return; }
    i -= 524288;
    if (i < 262144){ int n=i>>9, k=i&511; w_qT[i] = f2bf(w_q[k*512+n]); return; }
    i -= 262144;
    if (i < 262144){ int n=i>>9, k=i&511; w_combT[i] = f2bf(w_comb[k*512+n]); return; }
    i -= 262144;
    if (i < 16384){ int n=i>>7, k=i&127; float v=w0[k*128+n]; w0T_b[i]=f2bf(v); w0T_f[i]=v; return; }
    i -= 16384;
    if (i < 16384){ int n=i>>7, k=i&127; float v=w1[k*128+n]; w1T_b[i]=f2bf(v); w1T_f[i]=v; return; }
    i -= 16384;
    if (i < 16384){ w1row_b[i] = f2bf(w1[i]); return; }
    i -= 16384;
    if (i < BB*63*DIMM){
        int b = i/(63*DIMM); int r = i%(63*DIMM);
        int t = r>>9, d = r&511;
        outp[((size_t)b*LL + t)*DIMM + d] = empty[d];
        return;
    }
    i -= BB*63*DIMM;
    if (i < 1024){ if (i<512) amraw[i]=0.f; else dcraw[i-512]=0.f; }
}

// ---------------------------------------------------------------------------
// RMSNorm + lr/gate + chunk-stat partials via atomics. One wave per token,
// 2048 blocks (full occupancy). rc/gate stored pre-shifted by 63.
// ---------------------------------------------------------------------------
__global__ __launch_bounds__(256) void k_prep(
    const float* __restrict__ seq, const float* __restrict__ sscale,
    const float* __restrict__ rscale, const float* __restrict__ w_ada,
    const float* __restrict__ w_mom, const float* __restrict__ w_dec,
    const float* __restrict__ w_gate, ushort_t* __restrict__ s,
    ushort_t* __restrict__ rc, float* __restrict__ lr, float* __restrict__ gate,
    float* __restrict__ amraw, float* __restrict__ dcraw)
{
    int tok = blockIdx.x*4 + (threadIdx.x>>6);
    int lane = threadIdx.x & 63;
    int b = tok >> 12, t = tok & 4095;
    const float* x = seq + (size_t)tok*DIMM;
    float v[8]; float ss = 0.f;
    #pragma unroll
    for (int j=0;j<8;j++){ v[j] = x[lane + 64*j]; ss += v[j]*v[j]; }
    #pragma unroll
    for (int m=1;m<64;m<<=1) ss += __shfl_xor(ss, m, 64);
    float rstd = rsqrtf(ss * (1.0f/DIMM) + EPS_C);
    float pa[4] = {0,0,0,0}, pg[4] = {0,0,0,0};
    float pm[4] = {0,0,0,0}, pd[4] = {0,0,0,0};
    ushort_t se[8], re[8];
    #pragma unroll
    for (int j=0;j<8;j++){
        int d = lane + 64*j;
        float nv = v[j]*rstd;
        float sv = nv * sscale[d];
        float rv = nv * rscale[d];
        se[j] = f2bf(sv); re[j] = f2bf(rv);
        #pragma unroll
        for (int hh=0;hh<4;hh++){
            pa[hh] += sv*w_ada[d*4+hh];
            pg[hh] += rv*w_gate[d*4+hh];
            pm[hh] += sv*w_mom[d*4+hh];
            pd[hh] += sv*w_dec[d*4+hh];
        }
    }
    ushort_t* srow = s + (size_t)tok*DIMM;
    #pragma unroll
    for (int j=0;j<8;j++) srow[lane+64*j] = se[j];
    if (t >= 63){
        ushort_t* rrow = rc + ((size_t)b*LL + (t-63))*DIMM;
        #pragma unroll
        for (int j=0;j<8;j++) rrow[lane+64*j] = re[j];
    } else {
        ushort_t* rrow = rc + ((size_t)b*LL + (LL-63+t))*DIMM;
        #pragma unroll
        for (int j=0;j<8;j++) rrow[lane+64*j] = 0;
    }
    #pragma unroll
    for (int hh=0;hh<4;hh++){
        #pragma unroll
        for (int m=1;m<64;m<<=1){
            pa[hh] += __shfl_xor(pa[hh], m, 64);
            pg[hh] += __shfl_xor(pg[hh], m, 64);
            pm[hh] += __shfl_xor(pm[hh], m, 64);
            pd[hh] += __shfl_xor(pd[hh], m, 64);
        }
    }
    if (lane < 4){
        int hh = lane;
        int n = t >> 6;
        lr[((size_t)(b*4+hh))*LL + t] = sigmoidf_(pa[hh]) * MAX_LR_C;
        if (t >= 63) gate[((size_t)b*LL + (t-63))*4 + hh] = sigmoidf_(pg[hh]);
        else         gate[((size_t)b*LL + (LL-63+t))*4 + hh] = 0.5f;
        atomicAdd(&amraw[(b*4+hh)*64 + n], pm[hh] * (1.0f/64.0f));
        atomicAdd(&dcraw[(b*4+hh)*64 + n], pd[hh] * (1.0f/64.0f));
    }
}

// ---------------------------------------------------------------------------
// bf16 MFMA GEMM, 128x256 tile, BK=32, K=512 fixed, global_load_lds staging.
// MODE 0 kv:   O1=keys[t][d] hm, O2=keysT[d][t] chunk, O3=vals[t][d] hm
// MODE 4 Q:    O1=q[t][d] head-major
// MODE 5 comb: FO=d_out fp32 with +63 shift
// ---------------------------------------------------------------------------
template<int MODE>
__global__ __launch_bounds__(256) void k_mm256(
    const ushort_t* __restrict__ A, const ushort_t* __restrict__ BT,
    ushort_t* __restrict__ O1, ushort_t* __restrict__ O2, ushort_t* __restrict__ O3,
    float* __restrict__ FO)
{
    const int K = 512;
    __shared__ ushort_t As[128*32];
    __shared__ ushort_t Bs[256*32];
    int tid = threadIdx.x;
    int w = tid>>6, l = tid&63;
    int row0 = blockIdx.y*128, col0 = blockIdx.x*256;
    int wm = (w>>1)*64, wn = (w&1)*128;
    int lr16 = l&15, q = l>>4;
    f32x4 acc[4][8] = {};
    int arow = l>>2;
    int akof = (l&3)<<3;
    const size_t rA0 = (size_t)(row0 + w*16 + arow)*(size_t)K + akof;
    const size_t rB0 = (size_t)(col0 + w*16 + arow)*(size_t)K + akof;
    for (int k0=0; k0<K; k0+=32){
        __builtin_amdgcn_global_load_lds((gas1_t)(const void*)(A + rA0 + k0),
                                         (las3_t)(void*)(As + w*512), 16, 0, 0);
        __builtin_amdgcn_global_load_lds((gas1_t)(const void*)(A + rA0 + (size_t)64*K + k0),
                                         (las3_t)(void*)(As + 2048 + w*512), 16, 0, 0);
        #pragma unroll
        for (int u=0;u<4;u++)
            __builtin_amdgcn_global_load_lds((gas1_t)(const void*)(BT + rB0 + (size_t)(64*u)*K + k0),
                                             (las3_t)(void*)(Bs + u*2048 + w*512), 16, 0, 0);
        __syncthreads();
        bf16x8 af[4], bfv[8];
        #pragma unroll
        for (int i=0;i<4;i++)
            af[i]  = *(const bf16x8*)&As[(wm + i*16 + lr16)*32 + q*8];
        #pragma unroll
        for (int j=0;j<8;j++)
            bfv[j] = *(const bf16x8*)&Bs[(wn + j*16 + lr16)*32 + q*8];
        #pragma unroll
        for (int i=0;i<4;i++)
            #pragma unroll
            for (int j=0;j<8;j++)
                acc[i][j] = __builtin_amdgcn_mfma_f32_16x16x32_bf16(af[i], bfv[j], acc[i][j], 0,0,0);
        __syncthreads();
    }
    #pragma unroll
    for (int i=0;i<4;i++){
        int trb = row0 + wm + i*16 + q*4;
        #pragma unroll
        for (int j=0;j<8;j++){
            int tcol = col0 + wn + j*16 + lr16;
            f32x4 v = acc[i][j];
            if constexpr (MODE==0){
                int bb = trb>>12, l0 = trb&4095;
                int hh = (tcol>>7)&3, dd = tcol&127;
                size_t hm = ((size_t)(bb*4+hh)*LL + l0)*128 + dd;
                ushort_t e0=f2bf(v[0]), e1=f2bf(v[1]), e2=f2bf(v[2]), e3=f2bf(v[3]);
                if (tcol < 512){
                    O1[hm]=e0; O1[hm+128]=e1; O1[hm+256]=e2; O1[hm+384]=e3;
                    int ch = (bb*4+hh)*64 + (l0>>6);
                    ushort4 pk; pk.x=e0; pk.y=e1; pk.z=e2; pk.w=e3;
                    *(ushort4*)&O2[(size_t)ch*8192 + dd*64 + (l0&63)] = pk;
                } else {
                    O3[hm]=e0; O3[hm+128]=e1; O3[hm+256]=e2; O3[hm+384]=e3;
                }
            } else if constexpr (MODE==4){
                int bb = trb>>12, l0 = trb&4095;
                int hh = tcol>>7, dd = tcol&127;
                size_t hm = ((size_t)(bb*4+hh)*LL + l0)*128 + dd;
                O1[hm]=f2bf(v[0]); O1[hm+128]=f2bf(v[1]); O1[hm+256]=f2bf(v[2]); O1[hm+384]=f2bf(v[3]);
            } else { // 5
                int bb = trb>>12;
                #pragma unroll
                for (int r=0;r<4;r++){
                    int t = (trb&4095)+r;
                    if (t < LL-63)
                        FO[((size_t)bb*LL + t + 63)*DIMM + tcol] = v[r];
                }
            }
        }
    }
}

// ---------------------------------------------------------------------------
// Fused per-chunk store pipeline. One block/chunk, 80KB LDS.
// ---------------------------------------------------------------------------
__global__ __launch_bounds__(256,2) void k_fused(
    const ushort_t* __restrict__ keys, const ushort_t* __restrict__ vals,
    const ushort_t* __restrict__ keysT, const ushort_t* __restrict__ w0T,
    const ushort_t* __restrict__ w1T, const ushort_t* __restrict__ w1row,
    const float* __restrict__ lr, ushort_t* __restrict__ G0,
    ushort_t* __restrict__ G1)
{
    __shared__ ushort_t sK[8192];
    __shared__ ushort_t sV[8192];
    __shared__ ushort_t sH[8192];
    __shared__ ushort_t sW[16384];
    int ch = blockIdx.x;
    int tid = threadIdx.x;
    int w = tid>>6, l = tid&63, lr16 = l&15, q = l>>4;
    const size_t R0 = (size_t)ch*64;

    auto load_w = [&](const ushort_t* Wg){
        #pragma unroll
        for (int u=0; u<8; u++){
            int flat = u*2048 + tid*8;
            int r_ = flat>>7, c = flat&127;
            int off = (r_<<7) | ((((c>>3) ^ (r_&15))<<3));
            *(uint4*)&sW[off] = *(const uint4*)&Wg[flat];
        }
    };

    #pragma unroll
    for (int it=0; it<4; it++){
        int flat = it*2048 + tid*8;
        int t = flat>>7, d = flat&127;
        int off = (t<<7) | ((((d>>3) ^ (t&15))<<3));
        *(uint4*)&sK[off] = *(const uint4*)&keys[(R0<<7) + flat];
        *(uint4*)&sV[off] = *(const uint4*)&vals[(R0<<7) + flat];
    }
    load_w(w0T);
    __syncthreads();

    // ---- Phase A: HT[i][t] = sum_a w0T[i][a] keys[t][a]
    f32x4 acc[2][4] = {};
    #pragma unroll
    for (int s=0; s<4; s++){
        bf16x8 af[2], bv[4];
        #pragma unroll
        for (int mi=0;mi<2;mi++){
            int r_ = w*32 + mi*16 + lr16;
            af[mi] = *(const bf16x8*)&sW[(r_<<7) | ((((s*4+q) ^ (r_&15))<<3))];
        }
        #pragma unroll
        for (int nj=0;nj<4;nj++){
            int t = nj*16 + lr16;
            bv[nj] = *(const bf16x8*)&sK[(t<<7) | ((((s*4+q) ^ (t&15))<<3))];
        }
        #pragma unroll
        for (int mi=0;mi<2;mi++)
            #pragma unroll
            for (int nj=0;nj<4;nj++)
                acc[mi][nj] = __builtin_amdgcn_mfma_f32_16x16x32_bf16(af[mi], bv[nj], acc[mi][nj], 0,0,0);
    }
    __syncthreads();
    f32x4 sp[2][4];
    #pragma unroll
    for (int mi=0;mi<2;mi++){
        int i0 = w*32 + mi*16 + q*4;
        #pragma unroll
        for (int nj=0;nj<4;nj++){
            int t = nj*16 + lr16;
            ushort_t e[4];
            #pragma unroll
            for (int r=0;r<4;r++){
                float hv = acc[mi][nj][r];
                float sg = sigmoidf_(hv);
                sp[mi][nj][r] = sg*(1.f + hv*(1.f - sg));
                e[r] = f2bf(hv*sg);
                sK[sw128x64(i0+r, t)] = e[r];
            }
            ushort4 pk; pk.x=e[0]; pk.y=e[1]; pk.z=e[2]; pk.w=e[3];
            *(ushort4*)&sH[(t<<7) | ((((i0>>3) ^ (t&15))<<3) | (i0&7))] = pk;
        }
    }
    load_w(w1T);
    __syncthreads();

    // ---- Phase B: PT[j][t] = sum_i w1T[j][i] siluH[t][i]
    float lrw[4];
    #pragma unroll
    for (int nj=0;nj<4;nj++) lrw[nj] = lr[R0 + nj*16 + lr16];
    f32x4 accb[2][4] = {};
    #pragma unroll
    for (int s=0; s<4; s++){
        bf16x8 af[2], bv[4];
        #pragma unroll
        for (int mi=0;mi<2;mi++){
            int r_ = w*32 + mi*16 + lr16;
            af[mi] = *(const bf16x8*)&sW[(r_<<7) | ((((s*4+q) ^ (r_&15))<<3))];
        }
        #pragma unroll
        for (int nj=0;nj<4;nj++){
            int t = nj*16 + lr16;
            bv[nj] = *(const bf16x8*)&sH[(t<<7) | ((((s*4+q) ^ (t&15))<<3))];
        }
        #pragma unroll
        for (int mi=0;mi<2;mi++)
            #pragma unroll
            for (int nj=0;nj<4;nj++)
                accb[mi][nj] = __builtin_amdgcn_mfma_f32_16x16x32_bf16(af[mi], bv[nj], accb[mi][nj], 0,0,0);
    }
    __syncthreads();
    #pragma unroll
    for (int mi=0;mi<2;mi++){
        int j0 = w*32 + mi*16 + q*4;
        #pragma unroll
        for (int nj=0;nj<4;nj++){
            int t = nj*16 + lr16;
            int voff = (t<<7) | ((((j0>>3) ^ (t&15))<<3) | (j0&7));
            ushort4 vv = *(ushort4*)&sV[voff];
            float vf[4] = {bf2f(vv.x), bf2f(vv.y), bf2f(vv.z), bf2f(vv.w)};
            ushort_t e[4];
            #pragma unroll
            for (int r=0;r<4;r++){
                float dp = 0.015625f * lrw[nj] * (accb[mi][nj][r] - vf[r]);
                e[r] = f2bf(dp);
                sH[sw128x64(j0+r, t)] = e[r];
            }
            ushort4 pk; pk.x=e[0]; pk.y=e[1]; pk.z=e[2]; pk.w=e[3];
            *(ushort4*)&sV[voff] = pk;
        }
    }
    load_w(w1row);
    __syncthreads();

    // ---- Phase C: g1T[j][i] = sum_t dPT[j][t] siluHT[i][t]
    {
        f32x4 accc[2][8] = {};
        #pragma unroll
        for (int k0=0;k0<64;k0+=32){
            bf16x8 af[2], bv[8];
            #pragma unroll
            for (int mi=0;mi<2;mi++){
                int j_ = w*32 + mi*16 + lr16;
                af[mi] = *(const bf16x8*)&sH[(j_<<6) | (((((k0>>3)+q) ^ (j_&7))<<3))];
            }
            #pragma unroll
            for (int nj=0;nj<8;nj++){
                int i_ = nj*16 + lr16;
                bv[nj] = *(const bf16x8*)&sK[(i_<<6) | (((((k0>>3)+q) ^ (i_&7))<<3))];
            }
            #pragma unroll
            for (int mi=0;mi<2;mi++)
                #pragma unroll
                for (int nj=0;nj<8;nj++)
                    accc[mi][nj] = __builtin_amdgcn_mfma_f32_16x16x32_bf16(af[mi], bv[nj], accc[mi][nj], 0,0,0);
        }
        #pragma unroll
        for (int mi=0;mi<2;mi++){
            int j0 = w*32 + mi*16 + q*4;
            #pragma unroll
            for (int nj=0;nj<8;nj++){
                int i_ = nj*16 + lr16;
                #pragma unroll
                for (int r=0;r<4;r++)
                    G1[(size_t)ch*16384 + (size_t)(j0+r)*128 + i_] = f2bf(accc[mi][nj][r]);
            }
        }
    }

    // ---- Phase D: dHT[i][t] = (sum_j w1[i][j] dP[t][j]) * sp[i][t]
    f32x4 accd[2][4] = {};
    #pragma unroll
    for (int s=0; s<4; s++){
        bf16x8 af[2], bv[4];
        #pragma unroll
        for (int mi=0;mi<2;mi++){
            int r_ = w*32 + mi*16 + lr16;
            af[mi] = *(const bf16x8*)&sW[(r_<<7) | ((((s*4+q) ^ (r_&15))<<3))];
        }
        #pragma unroll
        for (int nj=0;nj<4;nj++){
            int t = nj*16 + lr16;
            bv[nj] = *(const bf16x8*)&sV[(t<<7) | ((((s*4+q) ^ (t&15))<<3))];
        }
        #pragma unroll
        for (int mi=0;mi<2;mi++)
            #pragma unroll
            for (int nj=0;nj<4;nj++)
                accd[mi][nj] = __builtin_amdgcn_mfma_f32_16x16x32_bf16(af[mi], bv[nj], accd[mi][nj], 0,0,0);
    }
    __syncthreads();
    #pragma unroll
    for (int mi=0;mi<2;mi++){
        int i0 = w*32 + mi*16 + q*4;
        #pragma unroll
        for (int nj=0;nj<4;nj++){
            int t = nj*16 + lr16;
            #pragma unroll
            for (int r=0;r<4;r++)
                sV[sw128x64(i0+r, t)] = f2bf(accd[mi][nj][r] * sp[mi][nj][r]);
        }
    }
    #pragma unroll
    for (int it=0; it<4; it++){
        int flat = it*2048 + tid*8;
        int x = flat>>6, t = flat&63;
        int off = (x<<6) | ((((t>>3) ^ (x&7))<<3));
        *(uint4*)&sW[off] = *(const uint4*)&keysT[(size_t)ch*8192 + flat];
    }
    __syncthreads();

    // ---- Phase E: g0T[i][a] = sum_t dHT[i][t] keysT[a][t]
    {
        f32x4 acce[2][8] = {};
        #pragma unroll
        for (int k0=0;k0<64;k0+=32){
            bf16x8 af[2], bv[8];
            #pragma unroll
            for (int mi=0;mi<2;mi++){
                int i_ = w*32 + mi*16 + lr16;
                af[mi] = *(const bf16x8*)&sV[(i_<<6) | (((((k0>>3)+q) ^ (i_&7))<<3))];
            }
            #pragma unroll
            for (int nj=0;nj<8;nj++){
                int a_ = nj*16 + lr16;
                bv[nj] = *(const bf16x8*)&sW[(a_<<6) | (((((k0>>3)+q) ^ (a_&7))<<3))];
            }
            #pragma unroll
            for (int mi=0;mi<2;mi++)
                #pragma unroll
                for (int nj=0;nj<8;nj++)
                    acce[mi][nj] = __builtin_amdgcn_mfma_f32_16x16x32_bf16(af[mi], bv[nj], acce[mi][nj], 0,0,0);
        }
        #pragma unroll
        for (int mi=0;mi<2;mi++){
            int i0 = w*32 + mi*16 + q*4;
            #pragma unroll
            for (int nj=0;nj<8;nj++){
                int a_ = nj*16 + lr16;
                #pragma unroll
                for (int r=0;r<4;r++)
                    G0[(size_t)ch*16384 + (size_t)(i0+r)*128 + a_] = f2bf(acce[mi][nj][r]);
            }
        }
    }
}

// ---------------------------------------------------------------------------
// Both scans, ushort4-vectorized, 4-deep prefetch ring, coeffs in LDS.
// block -> (mat, bh, 1024-dim slice). 256 blocks total.
// ---------------------------------------------------------------------------
__global__ __launch_bounds__(256) void k_scan2(
    const ushort_t* __restrict__ G0, const ushort_t* __restrict__ G1,
    const float* __restrict__ w0T_f, const float* __restrict__ w1T_f,
    const float* __restrict__ amraw, const float* __restrict__ dcraw,
    ushort_t* __restrict__ wt0T, ushort_t* __restrict__ wt1T)
{
    int blk = blockIdx.x;
    int mat = blk>>7, bh = (blk>>4)&7, sl = blk&15;
    const ushort_t* G = mat ? G1 : G0;
    const float* winit = mat ? w1T_f : w0T_f;
    ushort_t* wt = mat ? wt1T : wt0T;
    __shared__ float aS[64], dS[64];
    if (threadIdx.x < 64) aS[threadIdx.x] = sigmoidf_(amraw[bh*64+threadIdx.x]);
    else if (threadIdx.x < 128) dS[threadIdx.x-64] = 1.f - sigmoidf_(dcraw[bh*64+threadIdx.x-64]);
    __syncthreads();
    int rem = sl*1024 + threadIdx.x*4;
    float4 wv = *(const float4*)&winit[rem];
    size_t base = (size_t)bh*64*16384 + rem;
    ushort4 ring[4];
    #pragma unroll
    for (int p=0;p<4;p++) ring[p] = *(const ushort4*)&G[base + (size_t)p*16384];
    float mom[4] = {0,0,0,0}, upd[4] = {0,0,0,0};
    size_t idx = base;
    for (int n4=0; n4<64; n4+=4){
        #pragma unroll
        for (int p=0;p<4;p++){
            ushort4 g = ring[p];
            if (n4 + 4 < 64) ring[p] = *(const ushort4*)&G[idx + (size_t)4*16384];
            float a = aS[n4+p], d1 = dS[n4+p];
            float su[4] = {-bf2f(g.x), -bf2f(g.y), -bf2f(g.z), -bf2f(g.w)};
            #pragma unroll
            for (int e=0;e<4;e++){
                mom[e] = a*mom[e] + su[e];
                upd[e] = d1*upd[e] + mom[e];
            }
            ushort4 o;
            o.x = f2bf(wv.x + upd[0]); o.y = f2bf(wv.y + upd[1]);
            o.z = f2bf(wv.z + upd[2]); o.w = f2bf(wv.w + upd[3]);
            *(ushort4*)&wt[idx] = o;
            idx += 16384;
        }
    }
}

// ---------------------------------------------------------------------------
// Retrieve: per chunk, out = silu(Q @ w0t) @ w1t, MH-RMSNorm*(gamma+1)*gate.
// ---------------------------------------------------------------------------
__global__ __launch_bounds__(256) void k_retr(
    const ushort_t* __restrict__ Q, const ushort_t* __restrict__ W0t,
    const ushort_t* __restrict__ W1t, const float* __restrict__ gamma,
    const float* __restrict__ gate, ushort_t* __restrict__ out_pre)
{
    int chunk = blockIdx.x;
    int bh = chunk>>6, n = chunk&63, b = bh>>2, h = bh&3;
    __shared__ ushort_t Qs[64*136];
    __shared__ ushort_t Ws[128*136];
    __shared__ ushort_t O1s[64*136];
    int tid = threadIdx.x;
    const ushort_t* Qb = Q + (size_t)chunk*8192;
    #pragma unroll
    for (int it=0; it<4; it++){
        int i = tid*8 + it*2048;
        int row=i>>7, c=i&127;
        *(uint4*)&Qs[row*136+c] = *(const uint4*)&Qb[i];
    }
    const ushort_t* W0b = W0t + (size_t)chunk*16384;
    #pragma unroll
    for (int it=0; it<8; it++){
        int i = tid*8 + it*2048;
        int row=i>>7, c=i&127;
        *(uint4*)&Ws[row*136+c] = *(const uint4*)&W0b[i];
    }
    __syncthreads();
    int w=tid>>6, l=tid&63, lr16=l&15, q=l>>4;
    f32x4 acc[8] = {};
    #pragma unroll
    for (int k0=0;k0<128;k0+=32){
        bf16x8 af = *(const bf16x8*)&Qs[(w*16+lr16)*136 + k0 + q*8];
        #pragma unroll
        for (int j=0;j<8;j++){
            bf16x8 bv = *(const bf16x8*)&Ws[(j*16+lr16)*136 + k0 + q*8];
            acc[j] = __builtin_amdgcn_mfma_f32_16x16x32_bf16(af, bv, acc[j], 0,0,0);
        }
    }
    #pragma unroll
    for (int j=0;j<8;j++){
        #pragma unroll
        for (int r=0;r<4;r++){
            float hv = acc[j][r];
            float sg = sigmoidf_(hv);
            O1s[(w*16+q*4+r)*136 + j*16+lr16] = f2bf(hv*sg);
        }
    }
    __syncthreads();
    const ushort_t* W1b = W1t + (size_t)chunk*16384;
    #pragma unroll
    for (int it=0; it<8; it++){
        int i = tid*8 + it*2048;
        int row=i>>7, c=i&127;
        *(uint4*)&Ws[row*136+c] = *(const uint4*)&W1b[i];
    }
    __syncthreads();
    f32x4 acc2[8] = {};
    #pragma unroll
    for (int k0=0;k0<128;k0+=32){
        bf16x8 af = *(const bf16x8*)&O1s[(w*16+lr16)*136 + k0 + q*8];
        #pragma unroll
        for (int j=0;j<8;j++){
            bf16x8 bv = *(const bf16x8*)&Ws[(j*16+lr16)*136 + k0 + q*8];
            acc2[j] = __builtin_amdgcn_mfma_f32_16x16x32_bf16(af, bv, acc2[j], 0,0,0);
        }
    }
    float ssq[4] = {0,0,0,0};
    #pragma unroll
    for (int j=0;j<8;j++)
        #pragma unroll
        for (int r=0;r<4;r++) ssq[r] += acc2[j][r]*acc2[j][r];
    #pragma unroll
    for (int r=0;r<4;r++){
        ssq[r] += __shfl_xor(ssq[r], 1, 64);
        ssq[r] += __shfl_xor(ssq[r], 2, 64);
        ssq[r] += __shfl_xor(ssq[r], 4, 64);
        ssq[r] += __shfl_xor(ssq[r], 8, 64);
    }
    int tok0 = n*64 + w*16 + q*4;
    #pragma unroll
    for (int r=0;r<4;r++){
        float rstd = rsqrtf(ssq[r]*(1.0f/128.0f) + EPS_C);
        float gv = gate[((size_t)b*LL + tok0 + r)*4 + h];
        #pragma unroll
        for (int j=0;j<8;j++){
            int d = j*16 + lr16;
            float val = acc2[j][r]*rstd*(gamma[h*128+d]+1.0f)*gv;
            out_pre[((size_t)b*LL + tok0 + r)*DIMM + h*128 + d] = f2bf(val);
        }
    }
}

extern "C" void kernel_launch(void* const* d_in, const int* in_sizes, int n_in,
                              void* d_out, int out_size, void* d_ws, size_t ws_size,
                              hipStream_t stream)
{
    (void)in_sizes; (void)n_in; (void)out_size; (void)ws_size;
    const float* seq    = (const float*)d_in[0];
    const float* sscale = (const float*)d_in[1];
    const float* rscale = (const float*)d_in[2];
    const float* w_q    = (const float*)d_in[3];
    const float* w_kv   = (const float*)d_in[4];
    const float* w_ada  = (const float*)d_in[5];
    const float* w_mom  = (const float*)d_in[6];
    const float* w_dec  = (const float*)d_in[7];
    const float* w0     = (const float*)d_in[8];
    const float* w1     = (const float*)d_in[9];
    const float* gamma  = (const float*)d_in[10];
    const float* w_gate = (const float*)d_in[11];
    const float* w_comb = (const float*)d_in[12];
    const float* empty  = (const float*)d_in[13];
    float* out = (float*)d_out;
    char* wsb = (char*)d_ws;

    ushort_t* bufS  = (ushort_t*)(wsb + 0);          // s
    ushort_t* bufK  = (ushort_t*)(wsb + 8388608);    // keys -> out_pre
    ushort_t* bufV  = (ushort_t*)(wsb + 16777216);   // vals
    ushort_t* bufKT = (ushort_t*)(wsb + 25165824);   // keysT
    ushort_t* bufRC = (ushort_t*)(wsb + 33554432);   // rc (shifted)
    ushort_t* bufQ  = (ushort_t*)(wsb + 41943040);   // q
    ushort_t* G0    = (ushort_t*)(wsb + 50331648);
    ushort_t* G1    = (ushort_t*)(wsb + 67108864);
    ushort_t* wt0T  = (ushort_t*)(wsb + 83886080);
    ushort_t* wt1T  = (ushort_t*)(wsb + 100663296);
    ushort_t* w_kvT   = (ushort_t*)(wsb + 117440512);
    ushort_t* w_qT    = (ushort_t*)(wsb + 118489088);
    ushort_t* w_combT = (ushort_t*)(wsb + 119013376);
    ushort_t* w0T_b   = (ushort_t*)(wsb + 119537664);
    ushort_t* w1T_b   = (ushort_t*)(wsb + 119570432);
    ushort_t* w1row_b = (ushort_t*)(wsb + 119603200);
    float* w0T_f = (float*)(wsb + 119635968);
    float* w1T_f = (float*)(wsb + 119701504);
    float* lrbuf = (float*)(wsb + 119767040);
    float* gtbuf = (float*)(wsb + 119898112);
    float* amraw = (float*)(wsb + 120029184);
    float* dcraw = (float*)(wsb + 120031232);

    k_convert<<<4544, 256, 0, stream>>>(w_kv, w_q, w_comb, w0, w1, empty,
        w_kvT, w_qT, w_combT, w0T_b, w1T_b, w1row_b, w0T_f, w1T_f,
        out, amraw, dcraw);
    k_prep<<<2048, 256, 0, stream>>>(seq, sscale, rscale, w_ada, w_mom, w_dec,
        w_gate, bufS, bufRC, lrbuf, gtbuf, amraw, dcraw);
    // kv: keys(bufK) keysT(bufKT) vals(bufV)
    k_mm256<0><<<dim3(4,64), 256, 0, stream>>>(bufS, w_kvT, bufK, bufKT, bufV, nullptr);
    // fused store pipeline -> g0T(G0), g1T(G1)
    k_fused<<<NCH, 256, 0, stream>>>(bufK, bufV, bufKT, w0T_b, w1T_b, w1row_b,
        lrbuf, G0, G1);
    // both scans -> wt0T / wt1T
    k_scan2<<<256, 256, 0, stream>>>(G0, G1, w0T_f, w1T_f, amraw, dcraw,
        wt0T, wt1T);
    // Q = rc @ w_q -> head-major (bufQ)
    k_mm256<4><<<dim3(2,64), 256, 0, stream>>>(bufRC, w_qT, bufQ, nullptr, nullptr, nullptr);
    // retrieve -> out_pre (bufK)
    k_retr<<<NCH, 256, 0, stream>>>(bufQ, wt0T, wt1T, gamma, gtbuf, bufK);
    // combine -> d_out (shifted); rows 0..62 filled by k_convert
    k_mm256<5><<<dim3(2,64), 256, 0, stream>>>(bufK, w_combT, nullptr, nullptr, nullptr, out);
}

// Round 6
// 248.201 us; speedup vs baseline: 1.0561x; 1.0561x over previous
//
#include <hip/hip_runtime.h>

typedef unsigned short ushort_t;
typedef __bf16 bf16x8 __attribute__((ext_vector_type(8)));
typedef float f32x4 __attribute__((ext_vector_type(4)));
typedef const __attribute__((address_space(1))) void* gas1_t;
typedef __attribute__((address_space(3))) void* las3_t;

#define BB 2
#define LL 4096
#define DIMM 512
#define TOK (BB*LL)      // 8192
#define NCH 512          // BH*N chunks
#define MAX_LR_C 0.01f
#define EPS_C 1e-6f

__device__ __forceinline__ float sigmoidf_(float x){ return 1.0f/(1.0f + __expf(-x)); }
__device__ __forceinline__ ushort_t f2bf(float f){
    unsigned u = __builtin_bit_cast(unsigned, f);
    unsigned r = u + 0x7FFFu + ((u>>16)&1u);
    return (ushort_t)(r>>16);
}
__device__ __forceinline__ float bf2f(ushort_t h){
    unsigned u = ((unsigned)h)<<16; return __builtin_bit_cast(float, u);
}

// swizzled LDS offsets (element units, bf16): <=2-way bank aliasing (free, m136)
__device__ __forceinline__ int sw64x128(int t, int d){
    return (t<<7) | ((((d>>3) ^ (t&15))<<3) | (d&7));
}
__device__ __forceinline__ int sw128x64(int x, int t){
    return (x<<6) | ((((t>>3) ^ (x&7))<<3) | (t&7));
}

// ---------------------------------------------------------------------------
// Weight conversion/transpose to bf16 + transposed fp32 prep tables +
// d_out empty-prefix fill + zero accumulators.
// ---------------------------------------------------------------------------
__global__ __launch_bounds__(256) void k_convert(
    const float* __restrict__ w_kv, const float* __restrict__ w_q,
    const float* __restrict__ w_comb, const float* __restrict__ w0,
    const float* __restrict__ w1, const float* __restrict__ empty,
    const float* __restrict__ w_ada, const float* __restrict__ w_gate,
    const float* __restrict__ w_mom, const float* __restrict__ w_dec,
    ushort_t* __restrict__ w_kvT, ushort_t* __restrict__ w_qT,
    ushort_t* __restrict__ w_combT, ushort_t* __restrict__ w0T_b,
    ushort_t* __restrict__ w1T_b, ushort_t* __restrict__ w1row_b,
    float* __restrict__ w0T_f, float* __restrict__ w1T_f,
    float* __restrict__ outp, float* __restrict__ amraw, float* __restrict__ dcraw,
    float* __restrict__ tblT)
{
    int i = blockIdx.x*256 + threadIdx.x;
    if (i < 524288){ int n=i>>9, k=i&511; w_kvT[i] = f2bf(w_kv[k*1024+n]); return; }
    i -= 524288;
    if (i < 262144){ int n=i>>9, k=i&511; w_qT[i] = f2bf(w_q[k*512+n]); return; }
    i -= 262144;
    if (i < 262144){ int n=i>>9, k=i&511; w_combT[i] = f2bf(w_comb[k*512+n]); return; }
    i -= 262144;
    if (i < 16384){ int n=i>>7, k=i&127; float v=w0[k*128+n]; w0T_b[i]=f2bf(v); w0T_f[i]=v; return; }
    i -= 16384;
    if (i < 16384){ int n=i>>7, k=i&127; float v=w1[k*128+n]; w1T_b[i]=f2bf(v); w1T_f[i]=v; return; }
    i -= 16384;
    if (i < 16384){ w1row_b[i] = f2bf(w1[i]); return; }
    i -= 16384;
    if (i < BB*63*DIMM){
        int b = i/(63*DIMM); int r = i%(63*DIMM);
        int t = r>>9, d = r&511;
        outp[((size_t)b*LL + t)*DIMM + d] = empty[d];
        return;
    }
    i -= BB*63*DIMM;
    if (i < 1024){ if (i<512) amraw[i]=0.f; else dcraw[i-512]=0.f; return; }
    i -= 1024;
    if (i < 8192){
        int tb = i>>11, r = i&2047, hh = r>>9, d = r&511;
        const float* src = (tb==0) ? w_ada : (tb==1) ? w_gate : (tb==2) ? w_mom : w_dec;
        tblT[i] = src[d*4+hh];
    }
}

// ---------------------------------------------------------------------------
// RMSNorm + lr/gate + chunk-stat partials via atomics. One wave per token,
// 2048 blocks. Projection tables pre-transposed -> coalesced loads.
// rc/gate stored pre-shifted by 63.
// ---------------------------------------------------------------------------
__global__ __launch_bounds__(256) void k_prep(
    const float* __restrict__ seq, const float* __restrict__ sscale,
    const float* __restrict__ rscale, const float* __restrict__ tblT,
    ushort_t* __restrict__ s, ushort_t* __restrict__ rc,
    float* __restrict__ lr, float* __restrict__ gate,
    float* __restrict__ amraw, float* __restrict__ dcraw)
{
    int tok = blockIdx.x*4 + (threadIdx.x>>6);
    int lane = threadIdx.x & 63;
    int b = tok >> 12, t = tok & 4095;
    const float* x = seq + (size_t)tok*DIMM;
    const float* tA = tblT;          // ada   [4][512]
    const float* tG = tblT + 2048;   // gate
    const float* tM = tblT + 4096;   // mom
    const float* tD = tblT + 6144;   // dec
    float v[8]; float ss = 0.f;
    #pragma unroll
    for (int j=0;j<8;j++){ v[j] = x[lane + 64*j]; ss += v[j]*v[j]; }
    #pragma unroll
    for (int m=1;m<64;m<<=1) ss += __shfl_xor(ss, m, 64);
    float rstd = rsqrtf(ss * (1.0f/DIMM) + EPS_C);
    float pa[4] = {0,0,0,0}, pg[4] = {0,0,0,0};
    float pm[4] = {0,0,0,0}, pd[4] = {0,0,0,0};
    ushort_t se[8], re[8];
    #pragma unroll
    for (int j=0;j<8;j++){
        int d = lane + 64*j;
        float nv = v[j]*rstd;
        float sv = nv * sscale[d];
        float rv = nv * rscale[d];
        se[j] = f2bf(sv); re[j] = f2bf(rv);
        #pragma unroll
        for (int hh=0;hh<4;hh++){
            pa[hh] += sv*tA[hh*512+d];
            pg[hh] += rv*tG[hh*512+d];
            pm[hh] += sv*tM[hh*512+d];
            pd[hh] += sv*tD[hh*512+d];
        }
    }
    ushort_t* srow = s + (size_t)tok*DIMM;
    #pragma unroll
    for (int j=0;j<8;j++) srow[lane+64*j] = se[j];
    if (t >= 63){
        ushort_t* rrow = rc + ((size_t)b*LL + (t-63))*DIMM;
        #pragma unroll
        for (int j=0;j<8;j++) rrow[lane+64*j] = re[j];
    } else {
        ushort_t* rrow = rc + ((size_t)b*LL + (LL-63+t))*DIMM;
        #pragma unroll
        for (int j=0;j<8;j++) rrow[lane+64*j] = 0;
    }
    #pragma unroll
    for (int hh=0;hh<4;hh++){
        #pragma unroll
        for (int m=1;m<64;m<<=1){
            pa[hh] += __shfl_xor(pa[hh], m, 64);
            pg[hh] += __shfl_xor(pg[hh], m, 64);
            pm[hh] += __shfl_xor(pm[hh], m, 64);
            pd[hh] += __shfl_xor(pd[hh], m, 64);
        }
    }
    if (lane < 4){
        int hh = lane;
        int n = t >> 6;
        lr[((size_t)(b*4+hh))*LL + t] = sigmoidf_(pa[hh]) * MAX_LR_C;
        if (t >= 63) gate[((size_t)b*LL + (t-63))*4 + hh] = sigmoidf_(pg[hh]);
        else         gate[((size_t)b*LL + (LL-63+t))*4 + hh] = 0.5f;
        atomicAdd(&amraw[(b*4+hh)*64 + n], pm[hh] * (1.0f/64.0f));
        atomicAdd(&dcraw[(b*4+hh)*64 + n], pd[hh] * (1.0f/64.0f));
    }
}

// ---------------------------------------------------------------------------
// bf16 MFMA GEMM (m97 structure): 128x128 tile, BK=32, global_load_lds staging.
// MODE 0 kv:   O1=keys[t][d] hm, O2=keysT[d][t] chunk, O3=vals[t][d] hm
// MODE 4 Q:    O1=q[t][d] head-major
// MODE 5 comb: FO=d_out fp32 with +63 shift
// ---------------------------------------------------------------------------
template<int MODE>
__global__ __launch_bounds__(256) void k_mm(
    const ushort_t* __restrict__ A, const ushort_t* __restrict__ BT,
    ushort_t* __restrict__ O1, ushort_t* __restrict__ O2, ushort_t* __restrict__ O3,
    float* __restrict__ FO, int M, int N, int K)
{
    __shared__ ushort_t As[128*32];
    __shared__ ushort_t Bs[128*32];
    int tid = threadIdx.x;
    int w = tid>>6, l = tid&63;
    int row0 = blockIdx.y*128, col0 = blockIdx.x*128;
    int wm = (w>>1)*64, wn = (w&1)*64;
    int lr16 = l&15, q = l>>4;
    f32x4 acc[4][4] = {};
    int arow = l>>2;
    int akof = (l&3)<<3;
    const size_t rA0 = (size_t)(row0 + w*16 + arow)*(size_t)K + akof;
    const size_t rA1 = rA0 + (size_t)64*K;
    const size_t rB0 = (size_t)(col0 + w*16 + arow)*(size_t)K + akof;
    const size_t rB1 = rB0 + (size_t)64*K;
    for (int k0=0; k0<K; k0+=32){
        __builtin_amdgcn_global_load_lds((gas1_t)(const void*)(A + rA0 + k0),
                                         (las3_t)(void*)(As + w*512), 16, 0, 0);
        __builtin_amdgcn_global_load_lds((gas1_t)(const void*)(A + rA1 + k0),
                                         (las3_t)(void*)(As + 2048 + w*512), 16, 0, 0);
        __builtin_amdgcn_global_load_lds((gas1_t)(const void*)(BT + rB0 + k0),
                                         (las3_t)(void*)(Bs + w*512), 16, 0, 0);
        __builtin_amdgcn_global_load_lds((gas1_t)(const void*)(BT + rB1 + k0),
                                         (las3_t)(void*)(Bs + 2048 + w*512), 16, 0, 0);
        __syncthreads();
        bf16x8 af[4], bfv[4];
        #pragma unroll
        for (int i=0;i<4;i++){
            af[i]  = *(const bf16x8*)&As[(wm + i*16 + lr16)*32 + q*8];
            bfv[i] = *(const bf16x8*)&Bs[(wn + i*16 + lr16)*32 + q*8];
        }
        #pragma unroll
        for (int i=0;i<4;i++)
            #pragma unroll
            for (int j=0;j<4;j++)
                acc[i][j] = __builtin_amdgcn_mfma_f32_16x16x32_bf16(af[i], bfv[j], acc[i][j], 0,0,0);
        __syncthreads();
    }
    #pragma unroll
    for (int i=0;i<4;i++){
        int trb = row0 + wm + i*16 + q*4;
        #pragma unroll
        for (int j=0;j<4;j++){
            int tcol = col0 + wn + j*16 + lr16;
            f32x4 v = acc[i][j];
            if constexpr (MODE==0){
                int bb = trb>>12, l0 = trb&4095;
                int hh = (tcol>>7)&3, dd = tcol&127;
                size_t hm = ((size_t)(bb*4+hh)*LL + l0)*128 + dd;
                ushort_t e0=f2bf(v[0]), e1=f2bf(v[1]), e2=f2bf(v[2]), e3=f2bf(v[3]);
                if (tcol < 512){
                    O1[hm]=e0; O1[hm+128]=e1; O1[hm+256]=e2; O1[hm+384]=e3;
                    int ch = (bb*4+hh)*64 + (l0>>6);
                    ushort4 pk; pk.x=e0; pk.y=e1; pk.z=e2; pk.w=e3;
                    *(ushort4*)&O2[(size_t)ch*8192 + dd*64 + (l0&63)] = pk;
                } else {
                    O3[hm]=e0; O3[hm+128]=e1; O3[hm+256]=e2; O3[hm+384]=e3;
                }
            } else if constexpr (MODE==4){
                int bb = trb>>12, l0 = trb&4095;
                int hh = tcol>>7, dd = tcol&127;
                size_t hm = ((size_t)(bb*4+hh)*LL + l0)*128 + dd;
                O1[hm]=f2bf(v[0]); O1[hm+128]=f2bf(v[1]); O1[hm+256]=f2bf(v[2]); O1[hm+384]=f2bf(v[3]);
            } else { // 5
                int bb = trb>>12;
                #pragma unroll
                for (int r=0;r<4;r++){
                    int t = (trb&4095)+r;
                    if (t < LL-63)
                        FO[((size_t)bb*LL + t + 63)*DIMM + tcol] = v[r];
                }
            }
        }
    }
}

// ---------------------------------------------------------------------------
// Fused per-chunk store pipeline. One block/chunk, 80KB LDS.
// ---------------------------------------------------------------------------
__global__ __launch_bounds__(256,2) void k_fused(
    const ushort_t* __restrict__ keys, const ushort_t* __restrict__ vals,
    const ushort_t* __restrict__ keysT, const ushort_t* __restrict__ w0T,
    const ushort_t* __restrict__ w1T, const ushort_t* __restrict__ w1row,
    const float* __restrict__ lr, ushort_t* __restrict__ G0,
    ushort_t* __restrict__ G1)
{
    __shared__ ushort_t sK[8192];
    __shared__ ushort_t sV[8192];
    __shared__ ushort_t sH[8192];
    __shared__ ushort_t sW[16384];
    int ch = blockIdx.x;
    int tid = threadIdx.x;
    int w = tid>>6, l = tid&63, lr16 = l&15, q = l>>4;
    const size_t R0 = (size_t)ch*64;

    auto load_w = [&](const ushort_t* Wg){
        #pragma unroll
        for (int u=0; u<8; u++){
            int flat = u*2048 + tid*8;
            int r_ = flat>>7, c = flat&127;
            int off = (r_<<7) | ((((c>>3) ^ (r_&15))<<3));
            *(uint4*)&sW[off] = *(const uint4*)&Wg[flat];
        }
    };

    #pragma unroll
    for (int it=0; it<4; it++){
        int flat = it*2048 + tid*8;
        int t = flat>>7, d = flat&127;
        int off = (t<<7) | ((((d>>3) ^ (t&15))<<3));
        *(uint4*)&sK[off] = *(const uint4*)&keys[(R0<<7) + flat];
        *(uint4*)&sV[off] = *(const uint4*)&vals[(R0<<7) + flat];
    }
    load_w(w0T);
    __syncthreads();

    // ---- Phase A: HT[i][t] = sum_a w0T[i][a] keys[t][a]
    f32x4 acc[2][4] = {};
    #pragma unroll
    for (int s=0; s<4; s++){
        bf16x8 af[2], bv[4];
        #pragma unroll
        for (int mi=0;mi<2;mi++){
            int r_ = w*32 + mi*16 + lr16;
            af[mi] = *(const bf16x8*)&sW[(r_<<7) | ((((s*4+q) ^ (r_&15))<<3))];
        }
        #pragma unroll
        for (int nj=0;nj<4;nj++){
            int t = nj*16 + lr16;
            bv[nj] = *(const bf16x8*)&sK[(t<<7) | ((((s*4+q) ^ (t&15))<<3))];
        }
        #pragma unroll
        for (int mi=0;mi<2;mi++)
            #pragma unroll
            for (int nj=0;nj<4;nj++)
                acc[mi][nj] = __builtin_amdgcn_mfma_f32_16x16x32_bf16(af[mi], bv[nj], acc[mi][nj], 0,0,0);
    }
    __syncthreads();
    f32x4 sp[2][4];
    #pragma unroll
    for (int mi=0;mi<2;mi++){
        int i0 = w*32 + mi*16 + q*4;
        #pragma unroll
        for (int nj=0;nj<4;nj++){
            int t = nj*16 + lr16;
            ushort_t e[4];
            #pragma unroll
            for (int r=0;r<4;r++){
                float hv = acc[mi][nj][r];
                float sg = sigmoidf_(hv);
                sp[mi][nj][r] = sg*(1.f + hv*(1.f - sg));
                e[r] = f2bf(hv*sg);
                sK[sw128x64(i0+r, t)] = e[r];
            }
            ushort4 pk; pk.x=e[0]; pk.y=e[1]; pk.z=e[2]; pk.w=e[3];
            *(ushort4*)&sH[(t<<7) | ((((i0>>3) ^ (t&15))<<3) | (i0&7))] = pk;
        }
    }
    load_w(w1T);
    __syncthreads();

    // ---- Phase B: PT[j][t] = sum_i w1T[j][i] siluH[t][i]
    float lrw[4];
    #pragma unroll
    for (int nj=0;nj<4;nj++) lrw[nj] = lr[R0 + nj*16 + lr16];
    f32x4 accb[2][4] = {};
    #pragma unroll
    for (int s=0; s<4; s++){
        bf16x8 af[2], bv[4];
        #pragma unroll
        for (int mi=0;mi<2;mi++){
            int r_ = w*32 + mi*16 + lr16;
            af[mi] = *(const bf16x8*)&sW[(r_<<7) | ((((s*4+q) ^ (r_&15))<<3))];
        }
        #pragma unroll
        for (int nj=0;nj<4;nj++){
            int t = nj*16 + lr16;
            bv[nj] = *(const bf16x8*)&sH[(t<<7) | ((((s*4+q) ^ (t&15))<<3))];
        }
        #pragma unroll
        for (int mi=0;mi<2;mi++)
            #pragma unroll
            for (int nj=0;nj<4;nj++)
                accb[mi][nj] = __builtin_amdgcn_mfma_f32_16x16x32_bf16(af[mi], bv[nj], accb[mi][nj], 0,0,0);
    }
    __syncthreads();
    #pragma unroll
    for (int mi=0;mi<2;mi++){
        int j0 = w*32 + mi*16 + q*4;
        #pragma unroll
        for (int nj=0;nj<4;nj++){
            int t = nj*16 + lr16;
            int voff = (t<<7) | ((((j0>>3) ^ (t&15))<<3) | (j0&7));
            ushort4 vv = *(ushort4*)&sV[voff];
            float vf[4] = {bf2f(vv.x), bf2f(vv.y), bf2f(vv.z), bf2f(vv.w)};
            ushort_t e[4];
            #pragma unroll
            for (int r=0;r<4;r++){
                float dp = 0.015625f * lrw[nj] * (accb[mi][nj][r] - vf[r]);
                e[r] = f2bf(dp);
                sH[sw128x64(j0+r, t)] = e[r];
            }
            ushort4 pk; pk.x=e[0]; pk.y=e[1]; pk.z=e[2]; pk.w=e[3];
            *(ushort4*)&sV[voff] = pk;
        }
    }
    load_w(w1row);
    __syncthreads();

    // ---- Phase C: g1T[j][i] = sum_t dPT[j][t] siluHT[i][t]
    {
        f32x4 accc[2][8] = {};
        #pragma unroll
        for (int k0=0;k0<64;k0+=32){
            bf16x8 af[2], bv[8];
            #pragma unroll
            for (int mi=0;mi<2;mi++){
                int j_ = w*32 + mi*16 + lr16;
                af[mi] = *(const bf16x8*)&sH[(j_<<6) | (((((k0>>3)+q) ^ (j_&7))<<3))];
            }
            #pragma unroll
            for (int nj=0;nj<8;nj++){
                int i_ = nj*16 + lr16;
                bv[nj] = *(const bf16x8*)&sK[(i_<<6) | (((((k0>>3)+q) ^ (i_&7))<<3))];
            }
            #pragma unroll
            for (int mi=0;mi<2;mi++)
                #pragma unroll
                for (int nj=0;nj<8;nj++)
                    accc[mi][nj] = __builtin_amdgcn_mfma_f32_16x16x32_bf16(af[mi], bv[nj], accc[mi][nj], 0,0,0);
        }
        #pragma unroll
        for (int mi=0;mi<2;mi++){
            int j0 = w*32 + mi*16 + q*4;
            #pragma unroll
            for (int nj=0;nj<8;nj++){
                int i_ = nj*16 + lr16;
                #pragma unroll
                for (int r=0;r<4;r++)
                    G1[(size_t)ch*16384 + (size_t)(j0+r)*128 + i_] = f2bf(accc[mi][nj][r]);
            }
        }
    }

    // ---- Phase D: dHT[i][t] = (sum_j w1[i][j] dP[t][j]) * sp[i][t]
    f32x4 accd[2][4] = {};
    #pragma unroll
    for (int s=0; s<4; s++){
        bf16x8 af[2], bv[4];
        #pragma unroll
        for (int mi=0;mi<2;mi++){
            int r_ = w*32 + mi*16 + lr16;
            af[mi] = *(const bf16x8*)&sW[(r_<<7) | ((((s*4+q) ^ (r_&15))<<3))];
        }
        #pragma unroll
        for (int nj=0;nj<4;nj++){
            int t = nj*16 + lr16;
            bv[nj] = *(const bf16x8*)&sV[(t<<7) | ((((s*4+q) ^ (t&15))<<3))];
        }
        #pragma unroll
        for (int mi=0;mi<2;mi++)
            #pragma unroll
            for (int nj=0;nj<4;nj++)
                accd[mi][nj] = __builtin_amdgcn_mfma_f32_16x16x32_bf16(af[mi], bv[nj], accd[mi][nj], 0,0,0);
    }
    __syncthreads();
    #pragma unroll
    for (int mi=0;mi<2;mi++){
        int i0 = w*32 + mi*16 + q*4;
        #pragma unroll
        for (int nj=0;nj<4;nj++){
            int t = nj*16 + lr16;
            #pragma unroll
            for (int r=0;r<4;r++)
                sV[sw128x64(i0+r, t)] = f2bf(accd[mi][nj][r] * sp[mi][nj][r]);
        }
    }
    #pragma unroll
    for (int it=0; it<4; it++){
        int flat = it*2048 + tid*8;
        int x = flat>>6, t = flat&63;
        int off = (x<<6) | ((((t>>3) ^ (x&7))<<3));
        *(uint4*)&sW[off] = *(const uint4*)&keysT[(size_t)ch*8192 + flat];
    }
    __syncthreads();

    // ---- Phase E: g0T[i][a] = sum_t dHT[i][t] keysT[a][t]
    {
        f32x4 acce[2][8] = {};
        #pragma unroll
        for (int k0=0;k0<64;k0+=32){
            bf16x8 af[2], bv[8];
            #pragma unroll
            for (int mi=0;mi<2;mi++){
                int i_ = w*32 + mi*16 + lr16;
                af[mi] = *(const bf16x8*)&sV[(i_<<6) | (((((k0>>3)+q) ^ (i_&7))<<3))];
            }
            #pragma unroll
            for (int nj=0;nj<8;nj++){
                int a_ = nj*16 + lr16;
                bv[nj] = *(const bf16x8*)&sW[(a_<<6) | (((((k0>>3)+q) ^ (a_&7))<<3))];
            }
            #pragma unroll
            for (int mi=0;mi<2;mi++)
                #pragma unroll
                for (int nj=0;nj<8;nj++)
                    acce[mi][nj] = __builtin_amdgcn_mfma_f32_16x16x32_bf16(af[mi], bv[nj], acce[mi][nj], 0,0,0);
        }
        #pragma unroll
        for (int mi=0;mi<2;mi++){
            int i0 = w*32 + mi*16 + q*4;
            #pragma unroll
            for (int nj=0;nj<8;nj++){
                int a_ = nj*16 + lr16;
                #pragma unroll
                for (int r=0;r<4;r++)
                    G0[(size_t)ch*16384 + (size_t)(i0+r)*128 + a_] = f2bf(acce[mi][nj][r]);
            }
        }
    }
}

// ---------------------------------------------------------------------------
// Both scans, ushort4-vectorized, 4-deep prefetch ring, coeffs in LDS.
// ---------------------------------------------------------------------------
__global__ __launch_bounds__(256) void k_scan2(
    const ushort_t* __restrict__ G0, const ushort_t* __restrict__ G1,
    const float* __restrict__ w0T_f, const float* __restrict__ w1T_f,
    const float* __restrict__ amraw, const float* __restrict__ dcraw,
    ushort_t* __restrict__ wt0T, ushort_t* __restrict__ wt1T)
{
    int blk = blockIdx.x;
    int mat = blk>>7, bh = (blk>>4)&7, sl = blk&15;
    const ushort_t* G = mat ? G1 : G0;
    const float* winit = mat ? w1T_f : w0T_f;
    ushort_t* wt = mat ? wt1T : wt0T;
    __shared__ float aS[64], dS[64];
    if (threadIdx.x < 64) aS[threadIdx.x] = sigmoidf_(amraw[bh*64+threadIdx.x]);
    else if (threadIdx.x < 128) dS[threadIdx.x-64] = 1.f - sigmoidf_(dcraw[bh*64+threadIdx.x-64]);
    __syncthreads();
    int rem = sl*1024 + threadIdx.x*4;
    float4 wv = *(const float4*)&winit[rem];
    size_t base = (size_t)bh*64*16384 + rem;
    ushort4 ring[4];
    #pragma unroll
    for (int p=0;p<4;p++) ring[p] = *(const ushort4*)&G[base + (size_t)p*16384];
    float mom[4] = {0,0,0,0}, upd[4] = {0,0,0,0};
    size_t idx = base;
    for (int n4=0; n4<64; n4+=4){
        #pragma unroll
        for (int p=0;p<4;p++){
            ushort4 g = ring[p];
            if (n4 + 4 < 64) ring[p] = *(const ushort4*)&G[idx + (size_t)4*16384];
            float a = aS[n4+p], d1 = dS[n4+p];
            float su[4] = {-bf2f(g.x), -bf2f(g.y), -bf2f(g.z), -bf2f(g.w)};
            #pragma unroll
            for (int e=0;e<4;e++){
                mom[e] = a*mom[e] + su[e];
                upd[e] = d1*upd[e] + mom[e];
            }
            ushort4 o;
            o.x = f2bf(wv.x + upd[0]); o.y = f2bf(wv.y + upd[1]);
            o.z = f2bf(wv.z + upd[2]); o.w = f2bf(wv.w + upd[3]);
            *(ushort4*)&wt[idx] = o;
            idx += 16384;
        }
    }
}

// ---------------------------------------------------------------------------
// Retrieve: per chunk, out = silu(Q @ w0t) @ w1t, MH-RMSNorm*(gamma+1)*gate.
// ---------------------------------------------------------------------------
__global__ __launch_bounds__(256) void k_retr(
    const ushort_t* __restrict__ Q, const ushort_t* __restrict__ W0t,
    const ushort_t* __restrict__ W1t, const float* __restrict__ gamma,
    const float* __restrict__ gate, ushort_t* __restrict__ out_pre)
{
    int chunk = blockIdx.x;
    int bh = chunk>>6, n = chunk&63, b = bh>>2, h = bh&3;
    __shared__ ushort_t Qs[64*136];
    __shared__ ushort_t Ws[128*136];
    __shared__ ushort_t O1s[64*136];
    int tid = threadIdx.x;
    const ushort_t* Qb = Q + (size_t)chunk*8192;
    #pragma unroll
    for (int it=0; it<4; it++){
        int i = tid*8 + it*2048;
        int row=i>>7, c=i&127;
        *(uint4*)&Qs[row*136+c] = *(const uint4*)&Qb[i];
    }
    const ushort_t* W0b = W0t + (size_t)chunk*16384;
    #pragma unroll
    for (int it=0; it<8; it++){
        int i = tid*8 + it*2048;
        int row=i>>7, c=i&127;
        *(uint4*)&Ws[row*136+c] = *(const uint4*)&W0b[i];
    }
    __syncthreads();
    int w=tid>>6, l=tid&63, lr16=l&15, q=l>>4;
    f32x4 acc[8] = {};
    #pragma unroll
    for (int k0=0;k0<128;k0+=32){
        bf16x8 af = *(const bf16x8*)&Qs[(w*16+lr16)*136 + k0 + q*8];
        #pragma unroll
        for (int j=0;j<8;j++){
            bf16x8 bv = *(const bf16x8*)&Ws[(j*16+lr16)*136 + k0 + q*8];
            acc[j] = __builtin_amdgcn_mfma_f32_16x16x32_bf16(af, bv, acc[j], 0,0,0);
        }
    }
    #pragma unroll
    for (int j=0;j<8;j++){
        #pragma unroll
        for (int r=0;r<4;r++){
            float hv = acc[j][r];
            float sg = sigmoidf_(hv);
            O1s[(w*16+q*4+r)*136 + j*16+lr16] = f2bf(hv*sg);
        }
    }
    __syncthreads();
    const ushort_t* W1b = W1t + (size_t)chunk*16384;
    #pragma unroll
    for (int it=0; it<8; it++){
        int i = tid*8 + it*2048;
        int row=i>>7, c=i&127;
        *(uint4*)&Ws[row*136+c] = *(const uint4*)&W1b[i];
    }
    __syncthreads();
    f32x4 acc2[8] = {};
    #pragma unroll
    for (int k0=0;k0<128;k0+=32){
        bf16x8 af = *(const bf16x8*)&O1s[(w*16+lr16)*136 + k0 + q*8];
        #pragma unroll
        for (int j=0;j<8;j++){
            bf16x8 bv = *(const bf16x8*)&Ws[(j*16+lr16)*136 + k0 + q*8];
            acc2[j] = __builtin_amdgcn_mfma_f32_16x16x32_bf16(af, bv, acc2[j], 0,0,0);
        }
    }
    float ssq[4] = {0,0,0,0};
    #pragma unroll
    for (int j=0;j<8;j++)
        #pragma unroll
        for (int r=0;r<4;r++) ssq[r] += acc2[j][r]*acc2[j][r];
    #pragma unroll
    for (int r=0;r<4;r++){
        ssq[r] += __shfl_xor(ssq[r], 1, 64);
        ssq[r] += __shfl_xor(ssq[r], 2, 64);
        ssq[r] += __shfl_xor(ssq[r], 4, 64);
        ssq[r] += __shfl_xor(ssq[r], 8, 64);
    }
    int tok0 = n*64 + w*16 + q*4;
    #pragma unroll
    for (int r=0;r<4;r++){
        float rstd = rsqrtf(ssq[r]*(1.0f/128.0f) + EPS_C);
        float gv = gate[((size_t)b*LL + tok0 + r)*4 + h];
        #pragma unroll
        for (int j=0;j<8;j++){
            int d = j*16 + lr16;
            float val = acc2[j][r]*rstd*(gamma[h*128+d]+1.0f)*gv;
            out_pre[((size_t)b*LL + tok0 + r)*DIMM + h*128 + d] = f2bf(val);
        }
    }
}

extern "C" void kernel_launch(void* const* d_in, const int* in_sizes, int n_in,
                              void* d_out, int out_size, void* d_ws, size_t ws_size,
                              hipStream_t stream)
{
    (void)in_sizes; (void)n_in; (void)out_size; (void)ws_size;
    const float* seq    = (const float*)d_in[0];
    const float* sscale = (const float*)d_in[1];
    const float* rscale = (const float*)d_in[2];
    const float* w_q    = (const float*)d_in[3];
    const float* w_kv   = (const float*)d_in[4];
    const float* w_ada  = (const float*)d_in[5];
    const float* w_mom  = (const float*)d_in[6];
    const float* w_dec  = (const float*)d_in[7];
    const float* w0     = (const float*)d_in[8];
    const float* w1     = (const float*)d_in[9];
    const float* gamma  = (const float*)d_in[10];
    const float* w_gate = (const float*)d_in[11];
    const float* w_comb = (const float*)d_in[12];
    const float* empty  = (const float*)d_in[13];
    float* out = (float*)d_out;
    char* wsb = (char*)d_ws;

    ushort_t* bufS  = (ushort_t*)(wsb + 0);          // s
    ushort_t* bufK  = (ushort_t*)(wsb + 8388608);    // keys -> out_pre
    ushort_t* bufV  = (ushort_t*)(wsb + 16777216);   // vals
    ushort_t* bufKT = (ushort_t*)(wsb + 25165824);   // keysT
    ushort_t* bufRC = (ushort_t*)(wsb + 33554432);   // rc (shifted)
    ushort_t* bufQ  = (ushort_t*)(wsb + 41943040);   // q
    ushort_t* G0    = (ushort_t*)(wsb + 50331648);
    ushort_t* G1    = (ushort_t*)(wsb + 67108864);
    ushort_t* wt0T  = (ushort_t*)(wsb + 83886080);
    ushort_t* wt1T  = (ushort_t*)(wsb + 100663296);
    ushort_t* w_kvT   = (ushort_t*)(wsb + 117440512);
    ushort_t* w_qT    = (ushort_t*)(wsb + 118489088);
    ushort_t* w_combT = (ushort_t*)(wsb + 119013376);
    ushort_t* w0T_b   = (ushort_t*)(wsb + 119537664);
    ushort_t* w1T_b   = (ushort_t*)(wsb + 119570432);
    ushort_t* w1row_b = (ushort_t*)(wsb + 119603200);
    float* w0T_f = (float*)(wsb + 119635968);
    float* w1T_f = (float*)(wsb + 119701504);
    float* lrbuf = (float*)(wsb + 119767040);
    float* gtbuf = (float*)(wsb + 119898112);
    float* amraw = (float*)(wsb + 120029184);
    float* dcraw = (float*)(wsb + 120031232);
    float* tblT  = (float*)(wsb + 120033280);   // 32 KB [4][4][512]

    k_convert<<<4576, 256, 0, stream>>>(w_kv, w_q, w_comb, w0, w1, empty,
        w_ada, w_gate, w_mom, w_dec,
        w_kvT, w_qT, w_combT, w0T_b, w1T_b, w1row_b, w0T_f, w1T_f,
        out, amraw, dcraw, tblT);
    k_prep<<<2048, 256, 0, stream>>>(seq, sscale, rscale, tblT,
        bufS, bufRC, lrbuf, gtbuf, amraw, dcraw);
    // kv: keys(bufK) keysT(bufKT) vals(bufV)
    k_mm<0><<<dim3(8,64), 256, 0, stream>>>(bufS, w_kvT, bufK, bufKT, bufV,
        nullptr, 8192, 1024, 512);
    // fused store pipeline -> g0T(G0), g1T(G1)
    k_fused<<<NCH, 256, 0, stream>>>(bufK, bufV, bufKT, w0T_b, w1T_b, w1row_b,
        lrbuf, G0, G1);
    // both scans -> wt0T / wt1T
    k_scan2<<<256, 256, 0, stream>>>(G0, G1, w0T_f, w1T_f, amraw, dcraw,
        wt0T, wt1T);
    // Q = rc @ w_q -> head-major (bufQ)
    k_mm<4><<<dim3(4,64), 256, 0, stream>>>(bufRC, w_qT, bufQ, nullptr, nullptr,
        nullptr, 8192, 512, 512);
    // retrieve -> out_pre (bufK)
    k_retr<<<NCH, 256, 0, stream>>>(bufQ, wt0T, wt1T, gamma, gtbuf, bufK);
    // combine -> d_out (shifted); rows 0..62 filled by k_convert
    k_mm<5><<<dim3(4,64), 256, 0, stream>>>(bufK, w_combT, nullptr, nullptr, nullptr,
        out, 8192, 512, 512);
}

// Round 7
// 199.617 us; speedup vs baseline: 1.3131x; 1.2434x over previous
//
#include <hip/hip_runtime.h>

typedef unsigned short ushort_t;
typedef __bf16 bf16x8 __attribute__((ext_vector_type(8)));
typedef float f32x4 __attribute__((ext_vector_type(4)));
typedef const __attribute__((address_space(1))) void* gas1_t;
typedef __attribute__((address_space(3))) void* las3_t;

#define BB 2
#define LL 4096
#define DIMM 512
#define TOK (BB*LL)      // 8192
#define NCH 512          // BH*N chunks
#define MAX_LR_C 0.01f
#define EPS_C 1e-6f

__device__ __forceinline__ float sigmoidf_(float x){ return 1.0f/(1.0f + __expf(-x)); }
__device__ __forceinline__ ushort_t f2bf(float f){
    unsigned u = __builtin_bit_cast(unsigned, f);
    unsigned r = u + 0x7FFFu + ((u>>16)&1u);
    return (ushort_t)(r>>16);
}
__device__ __forceinline__ float bf2f(ushort_t h){
    unsigned u = ((unsigned)h)<<16; return __builtin_bit_cast(float, u);
}

// swizzled LDS offsets (element units, bf16): <=2-way bank aliasing (free, m136)
__device__ __forceinline__ int sw64x128(int t, int d){
    return (t<<7) | ((((d>>3) ^ (t&15))<<3) | (d&7));
}
__device__ __forceinline__ int sw128x64(int x, int t){
    return (x<<6) | ((((t>>3) ^ (x&7))<<3) | (t&7));
}

// ---------------------------------------------------------------------------
// Weight conversion/transpose to bf16 + projection tables (B-operand layout)
// + d_out empty-prefix fill.
// ---------------------------------------------------------------------------
__global__ __launch_bounds__(256) void k_convert(
    const float* __restrict__ w_kv, const float* __restrict__ w_q,
    const float* __restrict__ w_comb, const float* __restrict__ w0,
    const float* __restrict__ w1, const float* __restrict__ empty,
    const float* __restrict__ w_ada, const float* __restrict__ w_gate,
    const float* __restrict__ w_mom, const float* __restrict__ w_dec,
    ushort_t* __restrict__ w_kvT, ushort_t* __restrict__ w_qT,
    ushort_t* __restrict__ w_combT, ushort_t* __restrict__ w0T_b,
    ushort_t* __restrict__ w1T_b, ushort_t* __restrict__ w1row_b,
    float* __restrict__ w0T_f, float* __restrict__ w1T_f,
    float* __restrict__ outp, ushort_t* __restrict__ wtblS,
    ushort_t* __restrict__ wtblR)
{
    int i = blockIdx.x*256 + threadIdx.x;
    if (i < 524288){ int n=i>>9, k=i&511; w_kvT[i] = f2bf(w_kv[k*1024+n]); return; }
    i -= 524288;
    if (i < 262144){ int n=i>>9, k=i&511; w_qT[i] = f2bf(w_q[k*512+n]); return; }
    i -= 262144;
    if (i < 262144){ int n=i>>9, k=i&511; w_combT[i] = f2bf(w_comb[k*512+n]); return; }
    i -= 262144;
    if (i < 16384){ int n=i>>7, k=i&127; float v=w0[k*128+n]; w0T_b[i]=f2bf(v); w0T_f[i]=v; return; }
    i -= 16384;
    if (i < 16384){ int n=i>>7, k=i&127; float v=w1[k*128+n]; w1T_b[i]=f2bf(v); w1T_f[i]=v; return; }
    i -= 16384;
    if (i < 16384){ w1row_b[i] = f2bf(w1[i]); return; }
    i -= 16384;
    if (i < BB*63*DIMM){
        int b = i/(63*DIMM); int r = i%(63*DIMM);
        int t = r>>9, d = r&511;
        outp[((size_t)b*LL + t)*DIMM + d] = empty[d];
        return;
    }
    i -= BB*63*DIMM;
    if (i < 8192){
        int rrow = i>>9, d = i&511;
        float v = (rrow<4) ? w_ada[d*4+rrow] : (rrow<8) ? w_mom[d*4+rrow-4]
                : (rrow<12) ? w_dec[d*4+rrow-8] : 0.f;
        wtblS[i] = f2bf(v);
        return;
    }
    i -= 8192;
    if (i < 8192){
        int rrow = i>>9, d = i&511;
        float v = (rrow<4) ? w_gate[d*4+rrow] : 0.f;
        wtblR[i] = f2bf(v);
    }
}

// ---------------------------------------------------------------------------
// Pure streaming RMSNorm: s (store-norm) and rc (retrieve-norm, pre-shifted
// by 63 with zero tail). One wave/token, float4 in, ushort4 out. Nothing else.
// ---------------------------------------------------------------------------
__global__ __launch_bounds__(256) void k_norm(
    const float* __restrict__ seq, const float* __restrict__ sscale,
    const float* __restrict__ rscale, ushort_t* __restrict__ s,
    ushort_t* __restrict__ rc)
{
    int tok = blockIdx.x*4 + (threadIdx.x>>6);
    int lane = threadIdx.x & 63;
    int b = tok >> 12, t = tok & 4095;
    const float4* x4 = (const float4*)(seq + (size_t)tok*DIMM);
    float4 v0 = x4[lane], v1 = x4[lane+64];
    float ss = v0.x*v0.x + v0.y*v0.y + v0.z*v0.z + v0.w*v0.w
             + v1.x*v1.x + v1.y*v1.y + v1.z*v1.z + v1.w*v1.w;
    #pragma unroll
    for (int m=1;m<64;m<<=1) ss += __shfl_xor(ss, m, 64);
    float rstd = rsqrtf(ss * (1.0f/DIMM) + EPS_C);
    float4 sc0 = ((const float4*)sscale)[lane];
    float4 sc1 = ((const float4*)sscale)[lane+64];
    float4 rs0 = ((const float4*)rscale)[lane];
    float4 rs1 = ((const float4*)rscale)[lane+64];
    ushort4 se0, se1, re0, re1;
    se0.x = f2bf(v0.x*rstd*sc0.x); se0.y = f2bf(v0.y*rstd*sc0.y);
    se0.z = f2bf(v0.z*rstd*sc0.z); se0.w = f2bf(v0.w*rstd*sc0.w);
    se1.x = f2bf(v1.x*rstd*sc1.x); se1.y = f2bf(v1.y*rstd*sc1.y);
    se1.z = f2bf(v1.z*rstd*sc1.z); se1.w = f2bf(v1.w*rstd*sc1.w);
    re0.x = f2bf(v0.x*rstd*rs0.x); re0.y = f2bf(v0.y*rstd*rs0.y);
    re0.z = f2bf(v0.z*rstd*rs0.z); re0.w = f2bf(v0.w*rstd*rs0.w);
    re1.x = f2bf(v1.x*rstd*rs1.x); re1.y = f2bf(v1.y*rstd*rs1.y);
    re1.z = f2bf(v1.z*rstd*rs1.z); re1.w = f2bf(v1.w*rstd*rs1.w);
    ushort4* srow = (ushort4*)(s + (size_t)tok*DIMM);
    srow[lane] = se0; srow[lane+64] = se1;
    if (t >= 63){
        ushort4* rrow = (ushort4*)(rc + ((size_t)b*LL + (t-63))*DIMM);
        rrow[lane] = re0; rrow[lane+64] = re1;
    } else {
        ushort4* rrow = (ushort4*)(rc + ((size_t)b*LL + (LL-63+t))*DIMM);
        ushort4 z; z.x=0; z.y=0; z.z=0; z.w=0;
        rrow[lane] = z; rrow[lane+64] = z;
    }
}

// ---------------------------------------------------------------------------
// Projection GEMM via MFMA, frags straight from global (no LDS staging):
// blocks 0..127:  P = s_chunk(64x512) @ wtblS(16x512)^T -> lr (ada),
//                 per-chunk mom/dec sums -> amraw/dcraw (in-block, no atomics)
// blocks 128..255: P = rc_chunk @ wtblR^T -> gate (rc pre-shifted: tail rows
//                 are zero -> sigmoid(0)=0.5 automatically).
// ---------------------------------------------------------------------------
__global__ __launch_bounds__(256) void k_proj(
    const ushort_t* __restrict__ s, const ushort_t* __restrict__ rc,
    const ushort_t* __restrict__ wtblS, const ushort_t* __restrict__ wtblR,
    float* __restrict__ lr, float* __restrict__ gate,
    float* __restrict__ amraw, float* __restrict__ dcraw)
{
    __shared__ float ldsP[4][16];
    int item = blockIdx.x >> 7;
    int ch = blockIdx.x & 127;
    const ushort_t* A = item ? rc : s;
    const ushort_t* W = item ? wtblR : wtblS;
    int w = threadIdx.x>>6, l = threadIdx.x&63, c = l&15, q = l>>4;
    int row0 = ch*64 + w*16;
    const ushort_t* Arow = A + (size_t)(row0 + c)*DIMM + q*8;
    const ushort_t* Wrow = W + (size_t)c*DIMM + q*8;
    f32x4 acc = {};
    #pragma unroll
    for (int k0=0;k0<16;k0++){
        bf16x8 af = *(const bf16x8*)(Arow + k0*32);
        bf16x8 bv = *(const bf16x8*)(Wrow + k0*32);
        acc = __builtin_amdgcn_mfma_f32_16x16x32_bf16(af, bv, acc, 0,0,0);
    }
    if (item == 0){
        if (c < 4){
            #pragma unroll
            for (int r=0;r<4;r++){
                int G = row0 + q*4 + r;
                lr[(size_t)((G>>12)*4 + c)*LL + (G&4095)] = sigmoidf_(acc[r]) * MAX_LR_C;
            }
        }
        float s4v = acc[0]+acc[1]+acc[2]+acc[3];
        s4v += __shfl_xor(s4v, 16, 64);
        s4v += __shfl_xor(s4v, 32, 64);
        if (q == 0) ldsP[w][c] = s4v;
        __syncthreads();
        if (threadIdx.x < 16){
            float tot = ldsP[0][threadIdx.x]+ldsP[1][threadIdx.x]
                      + ldsP[2][threadIdx.x]+ldsP[3][threadIdx.x];
            int b2 = ch>>6, n = ch&63, cc = threadIdx.x;
            if (cc>=4 && cc<8)       amraw[(b2*4+(cc-4))*64 + n] = tot*(1.0f/64.0f);
            else if (cc>=8 && cc<12) dcraw[(b2*4+(cc-8))*64 + n] = tot*(1.0f/64.0f);
        }
    } else {
        if (c < 4){
            #pragma unroll
            for (int r=0;r<4;r++){
                int G = row0 + q*4 + r;
                gate[(size_t)G*4 + c] = sigmoidf_(acc[r]);
            }
        }
    }
}

// ---------------------------------------------------------------------------
// bf16 MFMA GEMM (m97 structure): 128x128 tile, BK=32, global_load_lds staging.
// XCD-aware swizzle: row-panel pinned to one XCD (assumes XCD = dispatch%8),
// so col-tiles sharing an A-panel hit the same L2.
// MODE 0 kv:   O1=keys[t][d] hm, O2=keysT[d][t] chunk, O3=vals[t][d] hm  (C=8)
// MODE 4 Q:    O1=q[t][d] head-major                                     (C=4)
// MODE 5 comb: FO=d_out fp32 with +63 shift                              (C=4)
// ---------------------------------------------------------------------------
template<int MODE>
__global__ __launch_bounds__(256) void k_mm(
    const ushort_t* __restrict__ A, const ushort_t* __restrict__ BT,
    ushort_t* __restrict__ O1, ushort_t* __restrict__ O2, ushort_t* __restrict__ O3,
    float* __restrict__ FO, int M, int N, int K)
{
    __shared__ ushort_t As[128*32];
    __shared__ ushort_t Bs[128*32];
    int tid = threadIdx.x;
    int w = tid>>6, l = tid&63;
    int ibl = blockIdx.x + blockIdx.y*gridDim.x;
    int x8 = ibl&7, m = ibl>>3;
    int row0, col0;
    if constexpr (MODE==0){ row0 = (x8 + ((m>>3)<<3))<<7; col0 = (m&7)<<7; }
    else                  { row0 = (x8 + ((m>>2)<<3))<<7; col0 = (m&3)<<7; }
    int wm = (w>>1)*64, wn = (w&1)*64;
    int lr16 = l&15, q = l>>4;
    f32x4 acc[4][4] = {};
    int arow = l>>2;
    int akof = (l&3)<<3;
    const size_t rA0 = (size_t)(row0 + w*16 + arow)*(size_t)K + akof;
    const size_t rA1 = rA0 + (size_t)64*K;
    const size_t rB0 = (size_t)(col0 + w*16 + arow)*(size_t)K + akof;
    const size_t rB1 = rB0 + (size_t)64*K;
    for (int k0=0; k0<K; k0+=32){
        __builtin_amdgcn_global_load_lds((gas1_t)(const void*)(A + rA0 + k0),
                                         (las3_t)(void*)(As + w*512), 16, 0, 0);
        __builtin_amdgcn_global_load_lds((gas1_t)(const void*)(A + rA1 + k0),
                                         (las3_t)(void*)(As + 2048 + w*512), 16, 0, 0);
        __builtin_amdgcn_global_load_lds((gas1_t)(const void*)(BT + rB0 + k0),
                                         (las3_t)(void*)(Bs + w*512), 16, 0, 0);
        __builtin_amdgcn_global_load_lds((gas1_t)(const void*)(BT + rB1 + k0),
                                         (las3_t)(void*)(Bs + 2048 + w*512), 16, 0, 0);
        __syncthreads();
        bf16x8 af[4], bfv[4];
        #pragma unroll
        for (int i=0;i<4;i++){
            af[i]  = *(const bf16x8*)&As[(wm + i*16 + lr16)*32 + q*8];
            bfv[i] = *(const bf16x8*)&Bs[(wn + i*16 + lr16)*32 + q*8];
        }
        #pragma unroll
        for (int i=0;i<4;i++)
            #pragma unroll
            for (int j=0;j<4;j++)
                acc[i][j] = __builtin_amdgcn_mfma_f32_16x16x32_bf16(af[i], bfv[j], acc[i][j], 0,0,0);
        __syncthreads();
    }
    #pragma unroll
    for (int i=0;i<4;i++){
        int trb = row0 + wm + i*16 + q*4;
        #pragma unroll
        for (int j=0;j<4;j++){
            int tcol = col0 + wn + j*16 + lr16;
            f32x4 v = acc[i][j];
            if constexpr (MODE==0){
                int bb = trb>>12, l0 = trb&4095;
                int hh = (tcol>>7)&3, dd = tcol&127;
                size_t hm = ((size_t)(bb*4+hh)*LL + l0)*128 + dd;
                ushort_t e0=f2bf(v[0]), e1=f2bf(v[1]), e2=f2bf(v[2]), e3=f2bf(v[3]);
                if (tcol < 512){
                    O1[hm]=e0; O1[hm+128]=e1; O1[hm+256]=e2; O1[hm+384]=e3;
                    int ch = (bb*4+hh)*64 + (l0>>6);
                    ushort4 pk; pk.x=e0; pk.y=e1; pk.z=e2; pk.w=e3;
                    *(ushort4*)&O2[(size_t)ch*8192 + dd*64 + (l0&63)] = pk;
                } else {
                    O3[hm]=e0; O3[hm+128]=e1; O3[hm+256]=e2; O3[hm+384]=e3;
                }
            } else if constexpr (MODE==4){
                int bb = trb>>12, l0 = trb&4095;
                int hh = tcol>>7, dd = tcol&127;
                size_t hm = ((size_t)(bb*4+hh)*LL + l0)*128 + dd;
                O1[hm]=f2bf(v[0]); O1[hm+128]=f2bf(v[1]); O1[hm+256]=f2bf(v[2]); O1[hm+384]=f2bf(v[3]);
            } else { // 5
                int bb = trb>>12;
                #pragma unroll
                for (int r=0;r<4;r++){
                    int t = (trb&4095)+r;
                    if (t < LL-63)
                        FO[((size_t)bb*LL + t + 63)*DIMM + tcol] = v[r];
                }
            }
        }
    }
}

// ---------------------------------------------------------------------------
// Fused per-chunk store pipeline. One block/chunk, 80KB LDS.
// ---------------------------------------------------------------------------
__global__ __launch_bounds__(256,2) void k_fused(
    const ushort_t* __restrict__ keys, const ushort_t* __restrict__ vals,
    const ushort_t* __restrict__ keysT, const ushort_t* __restrict__ w0T,
    const ushort_t* __restrict__ w1T, const ushort_t* __restrict__ w1row,
    const float* __restrict__ lr, ushort_t* __restrict__ G0,
    ushort_t* __restrict__ G1)
{
    __shared__ ushort_t sK[8192];
    __shared__ ushort_t sV[8192];
    __shared__ ushort_t sH[8192];
    __shared__ ushort_t sW[16384];
    int ch = blockIdx.x;
    int tid = threadIdx.x;
    int w = tid>>6, l = tid&63, lr16 = l&15, q = l>>4;
    const size_t R0 = (size_t)ch*64;

    auto load_w = [&](const ushort_t* Wg){
        #pragma unroll
        for (int u=0; u<8; u++){
            int flat = u*2048 + tid*8;
            int r_ = flat>>7, c = flat&127;
            int off = (r_<<7) | ((((c>>3) ^ (r_&15))<<3));
            *(uint4*)&sW[off] = *(const uint4*)&Wg[flat];
        }
    };

    #pragma unroll
    for (int it=0; it<4; it++){
        int flat = it*2048 + tid*8;
        int t = flat>>7, d = flat&127;
        int off = (t<<7) | ((((d>>3) ^ (t&15))<<3));
        *(uint4*)&sK[off] = *(const uint4*)&keys[(R0<<7) + flat];
        *(uint4*)&sV[off] = *(const uint4*)&vals[(R0<<7) + flat];
    }
    load_w(w0T);
    __syncthreads();

    // ---- Phase A: HT[i][t] = sum_a w0T[i][a] keys[t][a]
    f32x4 acc[2][4] = {};
    #pragma unroll
    for (int s=0; s<4; s++){
        bf16x8 af[2], bv[4];
        #pragma unroll
        for (int mi=0;mi<2;mi++){
            int r_ = w*32 + mi*16 + lr16;
            af[mi] = *(const bf16x8*)&sW[(r_<<7) | ((((s*4+q) ^ (r_&15))<<3))];
        }
        #pragma unroll
        for (int nj=0;nj<4;nj++){
            int t = nj*16 + lr16;
            bv[nj] = *(const bf16x8*)&sK[(t<<7) | ((((s*4+q) ^ (t&15))<<3))];
        }
        #pragma unroll
        for (int mi=0;mi<2;mi++)
            #pragma unroll
            for (int nj=0;nj<4;nj++)
                acc[mi][nj] = __builtin_amdgcn_mfma_f32_16x16x32_bf16(af[mi], bv[nj], acc[mi][nj], 0,0,0);
    }
    __syncthreads();
    f32x4 sp[2][4];
    #pragma unroll
    for (int mi=0;mi<2;mi++){
        int i0 = w*32 + mi*16 + q*4;
        #pragma unroll
        for (int nj=0;nj<4;nj++){
            int t = nj*16 + lr16;
            ushort_t e[4];
            #pragma unroll
            for (int r=0;r<4;r++){
                float hv = acc[mi][nj][r];
                float sg = sigmoidf_(hv);
                sp[mi][nj][r] = sg*(1.f + hv*(1.f - sg));
                e[r] = f2bf(hv*sg);
                sK[sw128x64(i0+r, t)] = e[r];
            }
            ushort4 pk; pk.x=e[0]; pk.y=e[1]; pk.z=e[2]; pk.w=e[3];
            *(ushort4*)&sH[(t<<7) | ((((i0>>3) ^ (t&15))<<3) | (i0&7))] = pk;
        }
    }
    load_w(w1T);
    __syncthreads();

    // ---- Phase B: PT[j][t] = sum_i w1T[j][i] siluH[t][i]
    float lrw[4];
    #pragma unroll
    for (int nj=0;nj<4;nj++) lrw[nj] = lr[R0 + nj*16 + lr16];
    f32x4 accb[2][4] = {};
    #pragma unroll
    for (int s=0; s<4; s++){
        bf16x8 af[2], bv[4];
        #pragma unroll
        for (int mi=0;mi<2;mi++){
            int r_ = w*32 + mi*16 + lr16;
            af[mi] = *(const bf16x8*)&sW[(r_<<7) | ((((s*4+q) ^ (r_&15))<<3))];
        }
        #pragma unroll
        for (int nj=0;nj<4;nj++){
            int t = nj*16 + lr16;
            bv[nj] = *(const bf16x8*)&sH[(t<<7) | ((((s*4+q) ^ (t&15))<<3))];
        }
        #pragma unroll
        for (int mi=0;mi<2;mi++)
            #pragma unroll
            for (int nj=0;nj<4;nj++)
                accb[mi][nj] = __builtin_amdgcn_mfma_f32_16x16x32_bf16(af[mi], bv[nj], accb[mi][nj], 0,0,0);
    }
    __syncthreads();
    #pragma unroll
    for (int mi=0;mi<2;mi++){
        int j0 = w*32 + mi*16 + q*4;
        #pragma unroll
        for (int nj=0;nj<4;nj++){
            int t = nj*16 + lr16;
            int voff = (t<<7) | ((((j0>>3) ^ (t&15))<<3) | (j0&7));
            ushort4 vv = *(ushort4*)&sV[voff];
            float vf[4] = {bf2f(vv.x), bf2f(vv.y), bf2f(vv.z), bf2f(vv.w)};
            ushort_t e[4];
            #pragma unroll
            for (int r=0;r<4;r++){
                float dp = 0.015625f * lrw[nj] * (accb[mi][nj][r] - vf[r]);
                e[r] = f2bf(dp);
                sH[sw128x64(j0+r, t)] = e[r];
            }
            ushort4 pk; pk.x=e[0]; pk.y=e[1]; pk.z=e[2]; pk.w=e[3];
            *(ushort4*)&sV[voff] = pk;
        }
    }
    load_w(w1row);
    __syncthreads();

    // ---- Phase C: g1T[j][i] = sum_t dPT[j][t] siluHT[i][t]
    {
        f32x4 accc[2][8] = {};
        #pragma unroll
        for (int k0=0;k0<64;k0+=32){
            bf16x8 af[2], bv[8];
            #pragma unroll
            for (int mi=0;mi<2;mi++){
                int j_ = w*32 + mi*16 + lr16;
                af[mi] = *(const bf16x8*)&sH[(j_<<6) | (((((k0>>3)+q) ^ (j_&7))<<3))];
            }
            #pragma unroll
            for (int nj=0;nj<8;nj++){
                int i_ = nj*16 + lr16;
                bv[nj] = *(const bf16x8*)&sK[(i_<<6) | (((((k0>>3)+q) ^ (i_&7))<<3))];
            }
            #pragma unroll
            for (int mi=0;mi<2;mi++)
                #pragma unroll
                for (int nj=0;nj<8;nj++)
                    accc[mi][nj] = __builtin_amdgcn_mfma_f32_16x16x32_bf16(af[mi], bv[nj], accc[mi][nj], 0,0,0);
        }
        #pragma unroll
        for (int mi=0;mi<2;mi++){
            int j0 = w*32 + mi*16 + q*4;
            #pragma unroll
            for (int nj=0;nj<8;nj++){
                int i_ = nj*16 + lr16;
                #pragma unroll
                for (int r=0;r<4;r++)
                    G1[(size_t)ch*16384 + (size_t)(j0+r)*128 + i_] = f2bf(accc[mi][nj][r]);
            }
        }
    }

    // ---- Phase D: dHT[i][t] = (sum_j w1[i][j] dP[t][j]) * sp[i][t]
    f32x4 accd[2][4] = {};
    #pragma unroll
    for (int s=0; s<4; s++){
        bf16x8 af[2], bv[4];
        #pragma unroll
        for (int mi=0;mi<2;mi++){
            int r_ = w*32 + mi*16 + lr16;
            af[mi] = *(const bf16x8*)&sW[(r_<<7) | ((((s*4+q) ^ (r_&15))<<3))];
        }
        #pragma unroll
        for (int nj=0;nj<4;nj++){
            int t = nj*16 + lr16;
            bv[nj] = *(const bf16x8*)&sV[(t<<7) | ((((s*4+q) ^ (t&15))<<3))];
        }
        #pragma unroll
        for (int mi=0;mi<2;mi++)
            #pragma unroll
            for (int nj=0;nj<4;nj++)
                accd[mi][nj] = __builtin_amdgcn_mfma_f32_16x16x32_bf16(af[mi], bv[nj], accd[mi][nj], 0,0,0);
    }
    __syncthreads();
    #pragma unroll
    for (int mi=0;mi<2;mi++){
        int i0 = w*32 + mi*16 + q*4;
        #pragma unroll
        for (int nj=0;nj<4;nj++){
            int t = nj*16 + lr16;
            #pragma unroll
            for (int r=0;r<4;r++)
                sV[sw128x64(i0+r, t)] = f2bf(accd[mi][nj][r] * sp[mi][nj][r]);
        }
    }
    #pragma unroll
    for (int it=0; it<4; it++){
        int flat = it*2048 + tid*8;
        int x = flat>>6, t = flat&63;
        int off = (x<<6) | ((((t>>3) ^ (x&7))<<3));
        *(uint4*)&sW[off] = *(const uint4*)&keysT[(size_t)ch*8192 + flat];
    }
    __syncthreads();

    // ---- Phase E: g0T[i][a] = sum_t dHT[i][t] keysT[a][t]
    {
        f32x4 acce[2][8] = {};
        #pragma unroll
        for (int k0=0;k0<64;k0+=32){
            bf16x8 af[2], bv[8];
            #pragma unroll
            for (int mi=0;mi<2;mi++){
                int i_ = w*32 + mi*16 + lr16;
                af[mi] = *(const bf16x8*)&sV[(i_<<6) | (((((k0>>3)+q) ^ (i_&7))<<3))];
            }
            #pragma unroll
            for (int nj=0;nj<8;nj++){
                int a_ = nj*16 + lr16;
                bv[nj] = *(const bf16x8*)&sW[(a_<<6) | (((((k0>>3)+q) ^ (a_&7))<<3))];
            }
            #pragma unroll
            for (int mi=0;mi<2;mi++)
                #pragma unroll
                for (int nj=0;nj<8;nj++)
                    acce[mi][nj] = __builtin_amdgcn_mfma_f32_16x16x32_bf16(af[mi], bv[nj], acce[mi][nj], 0,0,0);
        }
        #pragma unroll
        for (int mi=0;mi<2;mi++){
            int i0 = w*32 + mi*16 + q*4;
            #pragma unroll
            for (int nj=0;nj<8;nj++){
                int a_ = nj*16 + lr16;
                #pragma unroll
                for (int r=0;r<4;r++)
                    G0[(size_t)ch*16384 + (size_t)(i0+r)*128 + a_] = f2bf(acce[mi][nj][r]);
            }
        }
    }
}

// ---------------------------------------------------------------------------
// Both scans, ushort4-vectorized, 4-deep prefetch ring, coeffs in LDS.
// ---------------------------------------------------------------------------
__global__ __launch_bounds__(256) void k_scan2(
    const ushort_t* __restrict__ G0, const ushort_t* __restrict__ G1,
    const float* __restrict__ w0T_f, const float* __restrict__ w1T_f,
    const float* __restrict__ amraw, const float* __restrict__ dcraw,
    ushort_t* __restrict__ wt0T, ushort_t* __restrict__ wt1T)
{
    int blk = blockIdx.x;
    int mat = blk>>7, bh = (blk>>4)&7, sl = blk&15;
    const ushort_t* G = mat ? G1 : G0;
    const float* winit = mat ? w1T_f : w0T_f;
    ushort_t* wt = mat ? wt1T : wt0T;
    __shared__ float aS[64], dS[64];
    if (threadIdx.x < 64) aS[threadIdx.x] = sigmoidf_(amraw[bh*64+threadIdx.x]);
    else if (threadIdx.x < 128) dS[threadIdx.x-64] = 1.f - sigmoidf_(dcraw[bh*64+threadIdx.x-64]);
    __syncthreads();
    int rem = sl*1024 + threadIdx.x*4;
    float4 wv = *(const float4*)&winit[rem];
    size_t base = (size_t)bh*64*16384 + rem;
    ushort4 ring[4];
    #pragma unroll
    for (int p=0;p<4;p++) ring[p] = *(const ushort4*)&G[base + (size_t)p*16384];
    float mom[4] = {0,0,0,0}, upd[4] = {0,0,0,0};
    size_t idx = base;
    for (int n4=0; n4<64; n4+=4){
        #pragma unroll
        for (int p=0;p<4;p++){
            ushort4 g = ring[p];
            if (n4 + 4 < 64) ring[p] = *(const ushort4*)&G[idx + (size_t)4*16384];
            float a = aS[n4+p], d1 = dS[n4+p];
            float su[4] = {-bf2f(g.x), -bf2f(g.y), -bf2f(g.z), -bf2f(g.w)};
            #pragma unroll
            for (int e=0;e<4;e++){
                mom[e] = a*mom[e] + su[e];
                upd[e] = d1*upd[e] + mom[e];
            }
            ushort4 o;
            o.x = f2bf(wv.x + upd[0]); o.y = f2bf(wv.y + upd[1]);
            o.z = f2bf(wv.z + upd[2]); o.w = f2bf(wv.w + upd[3]);
            *(ushort4*)&wt[idx] = o;
            g = ring[p]; (void)g;
            idx += 16384;
        }
    }
}

// ---------------------------------------------------------------------------
// Retrieve: per chunk, out = silu(Q @ w0t) @ w1t, MH-RMSNorm*(gamma+1)*gate.
// ---------------------------------------------------------------------------
__global__ __launch_bounds__(256) void k_retr(
    const ushort_t* __restrict__ Q, const ushort_t* __restrict__ W0t,
    const ushort_t* __restrict__ W1t, const float* __restrict__ gamma,
    const float* __restrict__ gate, ushort_t* __restrict__ out_pre)
{
    int chunk = blockIdx.x;
    int bh = chunk>>6, n = chunk&63, b = bh>>2, h = bh&3;
    __shared__ ushort_t Qs[64*136];
    __shared__ ushort_t Ws[128*136];
    __shared__ ushort_t O1s[64*136];
    int tid = threadIdx.x;
    const ushort_t* Qb = Q + (size_t)chunk*8192;
    #pragma unroll
    for (int it=0; it<4; it++){
        int i = tid*8 + it*2048;
        int row=i>>7, c=i&127;
        *(uint4*)&Qs[row*136+c] = *(const uint4*)&Qb[i];
    }
    const ushort_t* W0b = W0t + (size_t)chunk*16384;
    #pragma unroll
    for (int it=0; it<8; it++){
        int i = tid*8 + it*2048;
        int row=i>>7, c=i&127;
        *(uint4*)&Ws[row*136+c] = *(const uint4*)&W0b[i];
    }
    __syncthreads();
    int w=tid>>6, l=tid&63, lr16=l&15, q=l>>4;
    f32x4 acc[8] = {};
    #pragma unroll
    for (int k0=0;k0<128;k0+=32){
        bf16x8 af = *(const bf16x8*)&Qs[(w*16+lr16)*136 + k0 + q*8];
        #pragma unroll
        for (int j=0;j<8;j++){
            bf16x8 bv = *(const bf16x8*)&Ws[(j*16+lr16)*136 + k0 + q*8];
            acc[j] = __builtin_amdgcn_mfma_f32_16x16x32_bf16(af, bv, acc[j], 0,0,0);
        }
    }
    #pragma unroll
    for (int j=0;j<8;j++){
        #pragma unroll
        for (int r=0;r<4;r++){
            float hv = acc[j][r];
            float sg = sigmoidf_(hv);
            O1s[(w*16+q*4+r)*136 + j*16+lr16] = f2bf(hv*sg);
        }
    }
    __syncthreads();
    const ushort_t* W1b = W1t + (size_t)chunk*16384;
    #pragma unroll
    for (int it=0; it<8; it++){
        int i = tid*8 + it*2048;
        int row=i>>7, c=i&127;
        *(uint4*)&Ws[row*136+c] = *(const uint4*)&W1b[i];
    }
    __syncthreads();
    f32x4 acc2[8] = {};
    #pragma unroll
    for (int k0=0;k0<128;k0+=32){
        bf16x8 af = *(const bf16x8*)&O1s[(w*16+lr16)*136 + k0 + q*8];
        #pragma unroll
        for (int j=0;j<8;j++){
            bf16x8 bv = *(const bf16x8*)&Ws[(j*16+lr16)*136 + k0 + q*8];
            acc2[j] = __builtin_amdgcn_mfma_f32_16x16x32_bf16(af, bv, acc2[j], 0,0,0);
        }
    }
    float ssq[4] = {0,0,0,0};
    #pragma unroll
    for (int j=0;j<8;j++)
        #pragma unroll
        for (int r=0;r<4;r++) ssq[r] += acc2[j][r]*acc2[j][r];
    #pragma unroll
    for (int r=0;r<4;r++){
        ssq[r] += __shfl_xor(ssq[r], 1, 64);
        ssq[r] += __shfl_xor(ssq[r], 2, 64);
        ssq[r] += __shfl_xor(ssq[r], 4, 64);
        ssq[r] += __shfl_xor(ssq[r], 8, 64);
    }
    int tok0 = n*64 + w*16 + q*4;
    #pragma unroll
    for (int r=0;r<4;r++){
        float rstd = rsqrtf(ssq[r]*(1.0f/128.0f) + EPS_C);
        float gv = gate[((size_t)b*LL + tok0 + r)*4 + h];
        #pragma unroll
        for (int j=0;j<8;j++){
            int d = j*16 + lr16;
            float val = acc2[j][r]*rstd*(gamma[h*128+d]+1.0f)*gv;
            out_pre[((size_t)b*LL + tok0 + r)*DIMM + h*128 + d] = f2bf(val);
        }
    }
}

extern "C" void kernel_launch(void* const* d_in, const int* in_sizes, int n_in,
                              void* d_out, int out_size, void* d_ws, size_t ws_size,
                              hipStream_t stream)
{
    (void)in_sizes; (void)n_in; (void)out_size; (void)ws_size;
    const float* seq    = (const float*)d_in[0];
    const float* sscale = (const float*)d_in[1];
    const float* rscale = (const float*)d_in[2];
    const float* w_q    = (const float*)d_in[3];
    const float* w_kv   = (const float*)d_in[4];
    const float* w_ada  = (const float*)d_in[5];
    const float* w_mom  = (const float*)d_in[6];
    const float* w_dec  = (const float*)d_in[7];
    const float* w0     = (const float*)d_in[8];
    const float* w1     = (const float*)d_in[9];
    const float* gamma  = (const float*)d_in[10];
    const float* w_gate = (const float*)d_in[11];
    const float* w_comb = (const float*)d_in[12];
    const float* empty  = (const float*)d_in[13];
    float* out = (float*)d_out;
    char* wsb = (char*)d_ws;

    ushort_t* bufS  = (ushort_t*)(wsb + 0);          // s
    ushort_t* bufK  = (ushort_t*)(wsb + 8388608);    // keys -> out_pre
    ushort_t* bufV  = (ushort_t*)(wsb + 16777216);   // vals
    ushort_t* bufKT = (ushort_t*)(wsb + 25165824);   // keysT
    ushort_t* bufRC = (ushort_t*)(wsb + 33554432);   // rc (shifted)
    ushort_t* bufQ  = (ushort_t*)(wsb + 41943040);   // q
    ushort_t* G0    = (ushort_t*)(wsb + 50331648);
    ushort_t* G1    = (ushort_t*)(wsb + 67108864);
    ushort_t* wt0T  = (ushort_t*)(wsb + 83886080);
    ushort_t* wt1T  = (ushort_t*)(wsb + 100663296);
    ushort_t* w_kvT   = (ushort_t*)(wsb + 117440512);
    ushort_t* w_qT    = (ushort_t*)(wsb + 118489088);
    ushort_t* w_combT = (ushort_t*)(wsb + 119013376);
    ushort_t* w0T_b   = (ushort_t*)(wsb + 119537664);
    ushort_t* w1T_b   = (ushort_t*)(wsb + 119570432);
    ushort_t* w1row_b = (ushort_t*)(wsb + 119603200);
    float* w0T_f = (float*)(wsb + 119635968);
    float* w1T_f = (float*)(wsb + 119701504);
    float* lrbuf = (float*)(wsb + 119767040);
    float* gtbuf = (float*)(wsb + 119898112);
    float* amraw = (float*)(wsb + 120029184);
    float* dcraw = (float*)(wsb + 120031232);
    ushort_t* wtblS = (ushort_t*)(wsb + 120033280);  // 16 KB [16][512] bf16
    ushort_t* wtblR = (ushort_t*)(wsb + 120049664);  // 16 KB [16][512] bf16

    k_convert<<<4604, 256, 0, stream>>>(w_kv, w_q, w_comb, w0, w1, empty,
        w_ada, w_gate, w_mom, w_dec,
        w_kvT, w_qT, w_combT, w0T_b, w1T_b, w1row_b, w0T_f, w1T_f,
        out, wtblS, wtblR);
    k_norm<<<2048, 256, 0, stream>>>(seq, sscale, rscale, bufS, bufRC);
    k_proj<<<256, 256, 0, stream>>>(bufS, bufRC, wtblS, wtblR,
        lrbuf, gtbuf, amraw, dcraw);
    // kv: keys(bufK) keysT(bufKT) vals(bufV)
    k_mm<0><<<dim3(8,64), 256, 0, stream>>>(bufS, w_kvT, bufK, bufKT, bufV,
        nullptr, 8192, 1024, 512);
    // fused store pipeline -> g0T(G0), g1T(G1)
    k_fused<<<NCH, 256, 0, stream>>>(bufK, bufV, bufKT, w0T_b, w1T_b, w1row_b,
        lrbuf, G0, G1);
    // both scans -> wt0T / wt1T
    k_scan2<<<256, 256, 0, stream>>>(G0, G1, w0T_f, w1T_f, amraw, dcraw,
        wt0T, wt1T);
    // Q = rc @ w_q -> head-major (bufQ)
    k_mm<4><<<dim3(4,64), 256, 0, stream>>>(bufRC, w_qT, bufQ, nullptr, nullptr,
        nullptr, 8192, 512, 512);
    // retrieve -> out_pre (bufK)
    k_retr<<<NCH, 256, 0, stream>>>(bufQ, wt0T, wt1T, gamma, gtbuf, bufK);
    // combine -> d_out (shifted); rows 0..62 filled by k_convert
    k_mm<5><<<dim3(4,64), 256, 0, stream>>>(bufK, w_combT, nullptr, nullptr, nullptr,
        out, 8192, 512, 512);
}

// Round 8
// 180.394 us; speedup vs baseline: 1.4530x; 1.1066x over previous
//
#include <hip/hip_runtime.h>

typedef unsigned short ushort_t;
typedef __bf16 bf16x8 __attribute__((ext_vector_type(8)));
typedef float f32x4 __attribute__((ext_vector_type(4)));
typedef const __attribute__((address_space(1))) void* gas1_t;
typedef __attribute__((address_space(3))) void* las3_t;

#define BB 2
#define LL 4096
#define DIMM 512
#define TOK (BB*LL)      // 8192
#define NCH 512          // BH*N chunks
#define MAX_LR_C 0.01f
#define EPS_C 1e-6f

__device__ __forceinline__ float sigmoidf_(float x){ return 1.0f/(1.0f + __expf(-x)); }
__device__ __forceinline__ ushort_t f2bf(float f){
    unsigned u = __builtin_bit_cast(unsigned, f);
    unsigned r = u + 0x7FFFu + ((u>>16)&1u);
    return (ushort_t)(r>>16);
}
__device__ __forceinline__ float bf2f(ushort_t h){
    unsigned u = ((unsigned)h)<<16; return __builtin_bit_cast(float, u);
}

// swizzled LDS offsets (element units, bf16): <=2-way bank aliasing (free, m136)
__device__ __forceinline__ int sw64x128(int t, int d){
    return (t<<7) | ((((d>>3) ^ (t&15))<<3) | (d&7));
}
__device__ __forceinline__ int sw128x64(int x, int t){
    return (x<<6) | ((((t>>3) ^ (x&7))<<3) | (t&7));
}

// ---------------------------------------------------------------------------
// k_init: blocks 0..2047 = streaming RMSNorm (s + pre-shifted rc);
// blocks 2048.. = weight convert/transpose + tables + d_out prefix fill.
// ---------------------------------------------------------------------------
__global__ __launch_bounds__(256) void k_init(
    const float* __restrict__ seq, const float* __restrict__ sscale,
    const float* __restrict__ rscale,
    const float* __restrict__ w_kv, const float* __restrict__ w_q,
    const float* __restrict__ w_comb, const float* __restrict__ w0,
    const float* __restrict__ w1, const float* __restrict__ empty,
    const float* __restrict__ w_ada, const float* __restrict__ w_gate,
    const float* __restrict__ w_mom, const float* __restrict__ w_dec,
    ushort_t* __restrict__ s, ushort_t* __restrict__ rc,
    ushort_t* __restrict__ w_kvT, ushort_t* __restrict__ w_qT,
    ushort_t* __restrict__ w_combT, ushort_t* __restrict__ w0T_b,
    ushort_t* __restrict__ w1T_b, ushort_t* __restrict__ w1row_b,
    float* __restrict__ w0T_f, float* __restrict__ w1T_f,
    float* __restrict__ outp, ushort_t* __restrict__ wtblS,
    ushort_t* __restrict__ wtblR)
{
    if (blockIdx.x < 2048){
        int tok = blockIdx.x*4 + (threadIdx.x>>6);
        int lane = threadIdx.x & 63;
        int b = tok >> 12, t = tok & 4095;
        const float4* x4 = (const float4*)(seq + (size_t)tok*DIMM);
        float4 v0 = x4[lane], v1 = x4[lane+64];
        float ss = v0.x*v0.x + v0.y*v0.y + v0.z*v0.z + v0.w*v0.w
                 + v1.x*v1.x + v1.y*v1.y + v1.z*v1.z + v1.w*v1.w;
        #pragma unroll
        for (int m=1;m<64;m<<=1) ss += __shfl_xor(ss, m, 64);
        float rstd = rsqrtf(ss * (1.0f/DIMM) + EPS_C);
        float4 sc0 = ((const float4*)sscale)[lane];
        float4 sc1 = ((const float4*)sscale)[lane+64];
        float4 rs0 = ((const float4*)rscale)[lane];
        float4 rs1 = ((const float4*)rscale)[lane+64];
        ushort4 se0, se1, re0, re1;
        se0.x = f2bf(v0.x*rstd*sc0.x); se0.y = f2bf(v0.y*rstd*sc0.y);
        se0.z = f2bf(v0.z*rstd*sc0.z); se0.w = f2bf(v0.w*rstd*sc0.w);
        se1.x = f2bf(v1.x*rstd*sc1.x); se1.y = f2bf(v1.y*rstd*sc1.y);
        se1.z = f2bf(v1.z*rstd*sc1.z); se1.w = f2bf(v1.w*rstd*sc1.w);
        re0.x = f2bf(v0.x*rstd*rs0.x); re0.y = f2bf(v0.y*rstd*rs0.y);
        re0.z = f2bf(v0.z*rstd*rs0.z); re0.w = f2bf(v0.w*rstd*rs0.w);
        re1.x = f2bf(v1.x*rstd*rs1.x); re1.y = f2bf(v1.y*rstd*rs1.y);
        re1.z = f2bf(v1.z*rstd*rs1.z); re1.w = f2bf(v1.w*rstd*rs1.w);
        ushort4* srow = (ushort4*)(s + (size_t)tok*DIMM);
        srow[lane] = se0; srow[lane+64] = se1;
        if (t >= 63){
            ushort4* rrow = (ushort4*)(rc + ((size_t)b*LL + (t-63))*DIMM);
            rrow[lane] = re0; rrow[lane+64] = re1;
        } else {
            ushort4* rrow = (ushort4*)(rc + ((size_t)b*LL + (LL-63+t))*DIMM);
            ushort4 z; z.x=0; z.y=0; z.z=0; z.w=0;
            rrow[lane] = z; rrow[lane+64] = z;
        }
        return;
    }
    int i = (blockIdx.x-2048)*256 + threadIdx.x;
    if (i < 524288){ int n=i>>9, k=i&511; w_kvT[i] = f2bf(w_kv[k*1024+n]); return; }
    i -= 524288;
    if (i < 262144){ int n=i>>9, k=i&511; w_qT[i] = f2bf(w_q[k*512+n]); return; }
    i -= 262144;
    if (i < 262144){ int n=i>>9, k=i&511; w_combT[i] = f2bf(w_comb[k*512+n]); return; }
    i -= 262144;
    if (i < 16384){ int n=i>>7, k=i&127; float v=w0[k*128+n]; w0T_b[i]=f2bf(v); w0T_f[i]=v; return; }
    i -= 16384;
    if (i < 16384){ int n=i>>7, k=i&127; float v=w1[k*128+n]; w1T_b[i]=f2bf(v); w1T_f[i]=v; return; }
    i -= 16384;
    if (i < 16384){ w1row_b[i] = f2bf(w1[i]); return; }
    i -= 16384;
    if (i < BB*63*DIMM){
        int b = i/(63*DIMM); int r = i%(63*DIMM);
        int t = r>>9, d = r&511;
        outp[((size_t)b*LL + t)*DIMM + d] = empty[d];
        return;
    }
    i -= BB*63*DIMM;
    if (i < 8192){
        int rrow = i>>9, d = i&511;
        float v = (rrow<4) ? w_ada[d*4+rrow] : (rrow<8) ? w_mom[d*4+rrow-4]
                : (rrow<12) ? w_dec[d*4+rrow-8] : 0.f;
        wtblS[i] = f2bf(v);
        return;
    }
    i -= 8192;
    if (i < 8192){
        int rrow = i>>9, d = i&511;
        float v = (rrow<4) ? w_gate[d*4+rrow] : 0.f;
        wtblR[i] = f2bf(v);
    }
}

// ---------------------------------------------------------------------------
// Shared 128x128 GEMM body (m97 structure), XCD-swizzled tiling.
// MODE 0 kv / MODE 4 Q / MODE 5 comb epilogues.
// ---------------------------------------------------------------------------
template<int MODE>
__device__ __forceinline__ void gemm_body(
    int ibl, ushort_t* As, ushort_t* Bs,
    const ushort_t* __restrict__ A, const ushort_t* __restrict__ BT,
    ushort_t* __restrict__ O1, ushort_t* __restrict__ O2, ushort_t* __restrict__ O3,
    float* __restrict__ FO, int K)
{
    int tid = threadIdx.x;
    int w = tid>>6, l = tid&63;
    int x8 = ibl&7, m = ibl>>3;
    int row0, col0;
    if constexpr (MODE==0){ row0 = (x8 + ((m>>3)<<3))<<7; col0 = (m&7)<<7; }
    else                  { row0 = (x8 + ((m>>2)<<3))<<7; col0 = (m&3)<<7; }
    int wm = (w>>1)*64, wn = (w&1)*64;
    int lr16 = l&15, q = l>>4;
    f32x4 acc[4][4] = {};
    int arow = l>>2;
    int akof = (l&3)<<3;
    const size_t rA0 = (size_t)(row0 + w*16 + arow)*(size_t)K + akof;
    const size_t rA1 = rA0 + (size_t)64*K;
    const size_t rB0 = (size_t)(col0 + w*16 + arow)*(size_t)K + akof;
    const size_t rB1 = rB0 + (size_t)64*K;
    for (int k0=0; k0<K; k0+=32){
        __builtin_amdgcn_global_load_lds((gas1_t)(const void*)(A + rA0 + k0),
                                         (las3_t)(void*)(As + w*512), 16, 0, 0);
        __builtin_amdgcn_global_load_lds((gas1_t)(const void*)(A + rA1 + k0),
                                         (las3_t)(void*)(As + 2048 + w*512), 16, 0, 0);
        __builtin_amdgcn_global_load_lds((gas1_t)(const void*)(BT + rB0 + k0),
                                         (las3_t)(void*)(Bs + w*512), 16, 0, 0);
        __builtin_amdgcn_global_load_lds((gas1_t)(const void*)(BT + rB1 + k0),
                                         (las3_t)(void*)(Bs + 2048 + w*512), 16, 0, 0);
        __syncthreads();
        bf16x8 af[4], bfv[4];
        #pragma unroll
        for (int i=0;i<4;i++){
            af[i]  = *(const bf16x8*)&As[(wm + i*16 + lr16)*32 + q*8];
            bfv[i] = *(const bf16x8*)&Bs[(wn + i*16 + lr16)*32 + q*8];
        }
        #pragma unroll
        for (int i=0;i<4;i++)
            #pragma unroll
            for (int j=0;j<4;j++)
                acc[i][j] = __builtin_amdgcn_mfma_f32_16x16x32_bf16(af[i], bfv[j], acc[i][j], 0,0,0);
        __syncthreads();
    }
    #pragma unroll
    for (int i=0;i<4;i++){
        int trb = row0 + wm + i*16 + q*4;
        #pragma unroll
        for (int j=0;j<4;j++){
            int tcol = col0 + wn + j*16 + lr16;
            f32x4 v = acc[i][j];
            if constexpr (MODE==0){
                int bb = trb>>12, l0 = trb&4095;
                int hh = (tcol>>7)&3, dd = tcol&127;
                size_t hm = ((size_t)(bb*4+hh)*LL + l0)*128 + dd;
                ushort_t e0=f2bf(v[0]), e1=f2bf(v[1]), e2=f2bf(v[2]), e3=f2bf(v[3]);
                if (tcol < 512){
                    O1[hm]=e0; O1[hm+128]=e1; O1[hm+256]=e2; O1[hm+384]=e3;
                    int ch = (bb*4+hh)*64 + (l0>>6);
                    ushort4 pk; pk.x=e0; pk.y=e1; pk.z=e2; pk.w=e3;
                    *(ushort4*)&O2[(size_t)ch*8192 + dd*64 + (l0&63)] = pk;
                } else {
                    O3[hm]=e0; O3[hm+128]=e1; O3[hm+256]=e2; O3[hm+384]=e3;
                }
            } else if constexpr (MODE==4){
                int bb = trb>>12, l0 = trb&4095;
                int hh = tcol>>7, dd = tcol&127;
                size_t hm = ((size_t)(bb*4+hh)*LL + l0)*128 + dd;
                O1[hm]=f2bf(v[0]); O1[hm+128]=f2bf(v[1]); O1[hm+256]=f2bf(v[2]); O1[hm+384]=f2bf(v[3]);
            } else { // 5
                int bb = trb>>12;
                #pragma unroll
                for (int r=0;r<4;r++){
                    int t = (trb&4095)+r;
                    if (t < LL-63)
                        FO[((size_t)bb*LL + t + 63)*DIMM + tcol] = v[r];
                }
            }
        }
    }
}

// ---------------------------------------------------------------------------
// k_gemms: blocks 0..511 kv GEMM, 512..767 Q GEMM, 768..1023 projections.
// All depend only on {k_init}. proj: lr/gate/amraw/dcraw via MFMA, in-block
// chunk sums (no atomics).
// ---------------------------------------------------------------------------
__global__ __launch_bounds__(256) void k_gemms(
    const ushort_t* __restrict__ s, const ushort_t* __restrict__ rc,
    const ushort_t* __restrict__ w_kvT, const ushort_t* __restrict__ w_qT,
    const ushort_t* __restrict__ wtblS, const ushort_t* __restrict__ wtblR,
    ushort_t* __restrict__ keys, ushort_t* __restrict__ keysT,
    ushort_t* __restrict__ vals, ushort_t* __restrict__ qbuf,
    float* __restrict__ lr, float* __restrict__ gate,
    float* __restrict__ amraw, float* __restrict__ dcraw)
{
    __shared__ ushort_t As[128*32];
    __shared__ ushort_t Bs[128*32];
    if (blockIdx.x < 512){
        gemm_body<0>(blockIdx.x, As, Bs, s, w_kvT, keys, keysT, vals, nullptr, 512);
        return;
    }
    if (blockIdx.x < 768){
        gemm_body<4>(blockIdx.x - 512, As, Bs, rc, w_qT, qbuf, nullptr, nullptr, nullptr, 512);
        return;
    }
    // ---- projections
    float* ldsP = (float*)As;   // [4][16]
    int item = (blockIdx.x - 768) >> 7;
    int ch = (blockIdx.x - 768) & 127;
    const ushort_t* A = item ? rc : s;
    const ushort_t* W = item ? wtblR : wtblS;
    int w = threadIdx.x>>6, l = threadIdx.x&63, c = l&15, q = l>>4;
    int row0 = ch*64 + w*16;
    const ushort_t* Arow = A + (size_t)(row0 + c)*DIMM + q*8;
    const ushort_t* Wrow = W + (size_t)c*DIMM + q*8;
    f32x4 acc = {};
    #pragma unroll
    for (int k0=0;k0<16;k0++){
        bf16x8 af = *(const bf16x8*)(Arow + k0*32);
        bf16x8 bv = *(const bf16x8*)(Wrow + k0*32);
        acc = __builtin_amdgcn_mfma_f32_16x16x32_bf16(af, bv, acc, 0,0,0);
    }
    if (item == 0){
        if (c < 4){
            #pragma unroll
            for (int r=0;r<4;r++){
                int G = row0 + q*4 + r;
                lr[(size_t)((G>>12)*4 + c)*LL + (G&4095)] = sigmoidf_(acc[r]) * MAX_LR_C;
            }
        }
        float s4v = acc[0]+acc[1]+acc[2]+acc[3];
        s4v += __shfl_xor(s4v, 16, 64);
        s4v += __shfl_xor(s4v, 32, 64);
        if (q == 0) ldsP[w*16 + c] = s4v;
        __syncthreads();
        if (threadIdx.x < 16){
            float tot = ldsP[threadIdx.x]+ldsP[16+threadIdx.x]
                      + ldsP[32+threadIdx.x]+ldsP[48+threadIdx.x];
            int b2 = ch>>6, n = ch&63, cc = threadIdx.x;
            if (cc>=4 && cc<8)       amraw[(b2*4+(cc-4))*64 + n] = tot*(1.0f/64.0f);
            else if (cc>=8 && cc<12) dcraw[(b2*4+(cc-8))*64 + n] = tot*(1.0f/64.0f);
        }
    } else {
        if (c < 4){
            #pragma unroll
            for (int r=0;r<4;r++){
                int G = row0 + q*4 + r;
                gate[(size_t)G*4 + c] = sigmoidf_(acc[r]);
            }
        }
    }
}

// ---------------------------------------------------------------------------
// Standalone 128x128 GEMM wrapper (combine).
// ---------------------------------------------------------------------------
template<int MODE>
__global__ __launch_bounds__(256) void k_mm(
    const ushort_t* __restrict__ A, const ushort_t* __restrict__ BT,
    ushort_t* __restrict__ O1, ushort_t* __restrict__ O2, ushort_t* __restrict__ O3,
    float* __restrict__ FO, int K)
{
    __shared__ ushort_t As[128*32];
    __shared__ ushort_t Bs[128*32];
    int ibl = blockIdx.x + blockIdx.y*gridDim.x;
    gemm_body<MODE>(ibl, As, Bs, A, BT, O1, O2, O3, FO, K);
}

// ---------------------------------------------------------------------------
// Fused per-chunk store pipeline. One block/chunk, 80KB LDS.
// ---------------------------------------------------------------------------
__global__ __launch_bounds__(256,2) void k_fused(
    const ushort_t* __restrict__ keys, const ushort_t* __restrict__ vals,
    const ushort_t* __restrict__ keysT, const ushort_t* __restrict__ w0T,
    const ushort_t* __restrict__ w1T, const ushort_t* __restrict__ w1row,
    const float* __restrict__ lr, ushort_t* __restrict__ G0,
    ushort_t* __restrict__ G1)
{
    __shared__ ushort_t sK[8192];
    __shared__ ushort_t sV[8192];
    __shared__ ushort_t sH[8192];
    __shared__ ushort_t sW[16384];
    int ch = blockIdx.x;
    int tid = threadIdx.x;
    int w = tid>>6, l = tid&63, lr16 = l&15, q = l>>4;
    const size_t R0 = (size_t)ch*64;

    auto load_w = [&](const ushort_t* Wg){
        #pragma unroll
        for (int u=0; u<8; u++){
            int flat = u*2048 + tid*8;
            int r_ = flat>>7, c = flat&127;
            int off = (r_<<7) | ((((c>>3) ^ (r_&15))<<3));
            *(uint4*)&sW[off] = *(const uint4*)&Wg[flat];
        }
    };

    #pragma unroll
    for (int it=0; it<4; it++){
        int flat = it*2048 + tid*8;
        int t = flat>>7, d = flat&127;
        int off = (t<<7) | ((((d>>3) ^ (t&15))<<3));
        *(uint4*)&sK[off] = *(const uint4*)&keys[(R0<<7) + flat];
        *(uint4*)&sV[off] = *(const uint4*)&vals[(R0<<7) + flat];
    }
    load_w(w0T);
    __syncthreads();

    // ---- Phase A: HT[i][t] = sum_a w0T[i][a] keys[t][a]
    f32x4 acc[2][4] = {};
    #pragma unroll
    for (int s=0; s<4; s++){
        bf16x8 af[2], bv[4];
        #pragma unroll
        for (int mi=0;mi<2;mi++){
            int r_ = w*32 + mi*16 + lr16;
            af[mi] = *(const bf16x8*)&sW[(r_<<7) | ((((s*4+q) ^ (r_&15))<<3))];
        }
        #pragma unroll
        for (int nj=0;nj<4;nj++){
            int t = nj*16 + lr16;
            bv[nj] = *(const bf16x8*)&sK[(t<<7) | ((((s*4+q) ^ (t&15))<<3))];
        }
        #pragma unroll
        for (int mi=0;mi<2;mi++)
            #pragma unroll
            for (int nj=0;nj<4;nj++)
                acc[mi][nj] = __builtin_amdgcn_mfma_f32_16x16x32_bf16(af[mi], bv[nj], acc[mi][nj], 0,0,0);
    }
    __syncthreads();
    f32x4 sp[2][4];
    #pragma unroll
    for (int mi=0;mi<2;mi++){
        int i0 = w*32 + mi*16 + q*4;
        #pragma unroll
        for (int nj=0;nj<4;nj++){
            int t = nj*16 + lr16;
            ushort_t e[4];
            #pragma unroll
            for (int r=0;r<4;r++){
                float hv = acc[mi][nj][r];
                float sg = sigmoidf_(hv);
                sp[mi][nj][r] = sg*(1.f + hv*(1.f - sg));
                e[r] = f2bf(hv*sg);
                sK[sw128x64(i0+r, t)] = e[r];
            }
            ushort4 pk; pk.x=e[0]; pk.y=e[1]; pk.z=e[2]; pk.w=e[3];
            *(ushort4*)&sH[(t<<7) | ((((i0>>3) ^ (t&15))<<3) | (i0&7))] = pk;
        }
    }
    load_w(w1T);
    __syncthreads();

    // ---- Phase B: PT[j][t] = sum_i w1T[j][i] siluH[t][i]
    float lrw[4];
    #pragma unroll
    for (int nj=0;nj<4;nj++) lrw[nj] = lr[R0 + nj*16 + lr16];
    f32x4 accb[2][4] = {};
    #pragma unroll
    for (int s=0; s<4; s++){
        bf16x8 af[2], bv[4];
        #pragma unroll
        for (int mi=0;mi<2;mi++){
            int r_ = w*32 + mi*16 + lr16;
            af[mi] = *(const bf16x8*)&sW[(r_<<7) | ((((s*4+q) ^ (r_&15))<<3))];
        }
        #pragma unroll
        for (int nj=0;nj<4;nj++){
            int t = nj*16 + lr16;
            bv[nj] = *(const bf16x8*)&sH[(t<<7) | ((((s*4+q) ^ (t&15))<<3))];
        }
        #pragma unroll
        for (int mi=0;mi<2;mi++)
            #pragma unroll
            for (int nj=0;nj<4;nj++)
                accb[mi][nj] = __builtin_amdgcn_mfma_f32_16x16x32_bf16(af[mi], bv[nj], accb[mi][nj], 0,0,0);
    }
    __syncthreads();
    #pragma unroll
    for (int mi=0;mi<2;mi++){
        int j0 = w*32 + mi*16 + q*4;
        #pragma unroll
        for (int nj=0;nj<4;nj++){
            int t = nj*16 + lr16;
            int voff = (t<<7) | ((((j0>>3) ^ (t&15))<<3) | (j0&7));
            ushort4 vv = *(ushort4*)&sV[voff];
            float vf[4] = {bf2f(vv.x), bf2f(vv.y), bf2f(vv.z), bf2f(vv.w)};
            ushort_t e[4];
            #pragma unroll
            for (int r=0;r<4;r++){
                float dp = 0.015625f * lrw[nj] * (accb[mi][nj][r] - vf[r]);
                e[r] = f2bf(dp);
                sH[sw128x64(j0+r, t)] = e[r];
            }
            ushort4 pk; pk.x=e[0]; pk.y=e[1]; pk.z=e[2]; pk.w=e[3];
            *(ushort4*)&sV[voff] = pk;
        }
    }
    load_w(w1row);
    __syncthreads();

    // ---- Phase C: g1T[j][i] = sum_t dPT[j][t] siluHT[i][t]
    {
        f32x4 accc[2][8] = {};
        #pragma unroll
        for (int k0=0;k0<64;k0+=32){
            bf16x8 af[2], bv[8];
            #pragma unroll
            for (int mi=0;mi<2;mi++){
                int j_ = w*32 + mi*16 + lr16;
                af[mi] = *(const bf16x8*)&sH[(j_<<6) | (((((k0>>3)+q) ^ (j_&7))<<3))];
            }
            #pragma unroll
            for (int nj=0;nj<8;nj++){
                int i_ = nj*16 + lr16;
                bv[nj] = *(const bf16x8*)&sK[(i_<<6) | (((((k0>>3)+q) ^ (i_&7))<<3))];
            }
            #pragma unroll
            for (int mi=0;mi<2;mi++)
                #pragma unroll
                for (int nj=0;nj<8;nj++)
                    accc[mi][nj] = __builtin_amdgcn_mfma_f32_16x16x32_bf16(af[mi], bv[nj], accc[mi][nj], 0,0,0);
        }
        #pragma unroll
        for (int mi=0;mi<2;mi++){
            int j0 = w*32 + mi*16 + q*4;
            #pragma unroll
            for (int nj=0;nj<8;nj++){
                int i_ = nj*16 + lr16;
                #pragma unroll
                for (int r=0;r<4;r++)
                    G1[(size_t)ch*16384 + (size_t)(j0+r)*128 + i_] = f2bf(accc[mi][nj][r]);
            }
        }
    }

    // ---- Phase D: dHT[i][t] = (sum_j w1[i][j] dP[t][j]) * sp[i][t]
    f32x4 accd[2][4] = {};
    #pragma unroll
    for (int s=0; s<4; s++){
        bf16x8 af[2], bv[4];
        #pragma unroll
        for (int mi=0;mi<2;mi++){
            int r_ = w*32 + mi*16 + lr16;
            af[mi] = *(const bf16x8*)&sW[(r_<<7) | ((((s*4+q) ^ (r_&15))<<3))];
        }
        #pragma unroll
        for (int nj=0;nj<4;nj++){
            int t = nj*16 + lr16;
            bv[nj] = *(const bf16x8*)&sV[(t<<7) | ((((s*4+q) ^ (t&15))<<3))];
        }
        #pragma unroll
        for (int mi=0;mi<2;mi++)
            #pragma unroll
            for (int nj=0;nj<4;nj++)
                accd[mi][nj] = __builtin_amdgcn_mfma_f32_16x16x32_bf16(af[mi], bv[nj], accd[mi][nj], 0,0,0);
    }
    __syncthreads();
    #pragma unroll
    for (int mi=0;mi<2;mi++){
        int i0 = w*32 + mi*16 + q*4;
        #pragma unroll
        for (int nj=0;nj<4;nj++){
            int t = nj*16 + lr16;
            #pragma unroll
            for (int r=0;r<4;r++)
                sV[sw128x64(i0+r, t)] = f2bf(accd[mi][nj][r] * sp[mi][nj][r]);
        }
    }
    #pragma unroll
    for (int it=0; it<4; it++){
        int flat = it*2048 + tid*8;
        int x = flat>>6, t = flat&63;
        int off = (x<<6) | ((((t>>3) ^ (x&7))<<3));
        *(uint4*)&sW[off] = *(const uint4*)&keysT[(size_t)ch*8192 + flat];
    }
    __syncthreads();

    // ---- Phase E: g0T[i][a] = sum_t dHT[i][t] keysT[a][t]
    {
        f32x4 acce[2][8] = {};
        #pragma unroll
        for (int k0=0;k0<64;k0+=32){
            bf16x8 af[2], bv[8];
            #pragma unroll
            for (int mi=0;mi<2;mi++){
                int i_ = w*32 + mi*16 + lr16;
                af[mi] = *(const bf16x8*)&sV[(i_<<6) | (((((k0>>3)+q) ^ (i_&7))<<3))];
            }
            #pragma unroll
            for (int nj=0;nj<8;nj++){
                int a_ = nj*16 + lr16;
                bv[nj] = *(const bf16x8*)&sW[(a_<<6) | (((((k0>>3)+q) ^ (a_&7))<<3))];
            }
            #pragma unroll
            for (int mi=0;mi<2;mi++)
                #pragma unroll
                for (int nj=0;nj<8;nj++)
                    acce[mi][nj] = __builtin_amdgcn_mfma_f32_16x16x32_bf16(af[mi], bv[nj], acce[mi][nj], 0,0,0);
        }
        #pragma unroll
        for (int mi=0;mi<2;mi++){
            int i0 = w*32 + mi*16 + q*4;
            #pragma unroll
            for (int nj=0;nj<8;nj++){
                int a_ = nj*16 + lr16;
                #pragma unroll
                for (int r=0;r<4;r++)
                    G0[(size_t)ch*16384 + (size_t)(i0+r)*128 + a_] = f2bf(acce[mi][nj][r]);
            }
        }
    }
}

// ---------------------------------------------------------------------------
// Both scans, ushort4-vectorized, 8-deep prefetch ring, coeffs in LDS.
// ---------------------------------------------------------------------------
__global__ __launch_bounds__(256) void k_scan2(
    const ushort_t* __restrict__ G0, const ushort_t* __restrict__ G1,
    const float* __restrict__ w0T_f, const float* __restrict__ w1T_f,
    const float* __restrict__ amraw, const float* __restrict__ dcraw,
    ushort_t* __restrict__ wt0T, ushort_t* __restrict__ wt1T)
{
    int blk = blockIdx.x;
    int mat = blk>>7, bh = (blk>>4)&7, sl = blk&15;
    const ushort_t* G = mat ? G1 : G0;
    const float* winit = mat ? w1T_f : w0T_f;
    ushort_t* wt = mat ? wt1T : wt0T;
    __shared__ float aS[64], dS[64];
    if (threadIdx.x < 64) aS[threadIdx.x] = sigmoidf_(amraw[bh*64+threadIdx.x]);
    else if (threadIdx.x < 128) dS[threadIdx.x-64] = 1.f - sigmoidf_(dcraw[bh*64+threadIdx.x-64]);
    __syncthreads();
    int rem = sl*1024 + threadIdx.x*4;
    float4 wv = *(const float4*)&winit[rem];
    size_t base = (size_t)bh*64*16384 + rem;
    ushort4 ring[8];
    #pragma unroll
    for (int p=0;p<8;p++) ring[p] = *(const ushort4*)&G[base + (size_t)p*16384];
    float mom[4] = {0,0,0,0}, upd[4] = {0,0,0,0};
    size_t idx = base;
    for (int n8=0; n8<64; n8+=8){
        #pragma unroll
        for (int p=0;p<8;p++){
            ushort4 g = ring[p];
            if (n8 + 8 < 64) ring[p] = *(const ushort4*)&G[idx + (size_t)8*16384];
            float a = aS[n8+p], d1 = dS[n8+p];
            float su[4] = {-bf2f(g.x), -bf2f(g.y), -bf2f(g.z), -bf2f(g.w)};
            #pragma unroll
            for (int e=0;e<4;e++){
                mom[e] = a*mom[e] + su[e];
                upd[e] = d1*upd[e] + mom[e];
            }
            ushort4 o;
            o.x = f2bf(wv.x + upd[0]); o.y = f2bf(wv.y + upd[1]);
            o.z = f2bf(wv.z + upd[2]); o.w = f2bf(wv.w + upd[3]);
            *(ushort4*)&wt[idx] = o;
            idx += 16384;
        }
    }
}

// ---------------------------------------------------------------------------
// Retrieve: per chunk, out = silu(Q @ w0t) @ w1t, MH-RMSNorm*(gamma+1)*gate.
// ---------------------------------------------------------------------------
__global__ __launch_bounds__(256) void k_retr(
    const ushort_t* __restrict__ Q, const ushort_t* __restrict__ W0t,
    const ushort_t* __restrict__ W1t, const float* __restrict__ gamma,
    const float* __restrict__ gate, ushort_t* __restrict__ out_pre)
{
    int chunk = blockIdx.x;
    int bh = chunk>>6, n = chunk&63, b = bh>>2, h = bh&3;
    __shared__ ushort_t Qs[64*136];
    __shared__ ushort_t Ws[128*136];
    __shared__ ushort_t O1s[64*136];
    int tid = threadIdx.x;
    const ushort_t* Qb = Q + (size_t)chunk*8192;
    #pragma unroll
    for (int it=0; it<4; it++){
        int i = tid*8 + it*2048;
        int row=i>>7, c=i&127;
        *(uint4*)&Qs[row*136+c] = *(const uint4*)&Qb[i];
    }
    const ushort_t* W0b = W0t + (size_t)chunk*16384;
    #pragma unroll
    for (int it=0; it<8; it++){
        int i = tid*8 + it*2048;
        int row=i>>7, c=i&127;
        *(uint4*)&Ws[row*136+c] = *(const uint4*)&W0b[i];
    }
    __syncthreads();
    int w=tid>>6, l=tid&63, lr16=l&15, q=l>>4;
    f32x4 acc[8] = {};
    #pragma unroll
    for (int k0=0;k0<128;k0+=32){
        bf16x8 af = *(const bf16x8*)&Qs[(w*16+lr16)*136 + k0 + q*8];
        #pragma unroll
        for (int j=0;j<8;j++){
            bf16x8 bv = *(const bf16x8*)&Ws[(j*16+lr16)*136 + k0 + q*8];
            acc[j] = __builtin_amdgcn_mfma_f32_16x16x32_bf16(af, bv, acc[j], 0,0,0);
        }
    }
    #pragma unroll
    for (int j=0;j<8;j++){
        #pragma unroll
        for (int r=0;r<4;r++){
            float hv = acc[j][r];
            float sg = sigmoidf_(hv);
            O1s[(w*16+q*4+r)*136 + j*16+lr16] = f2bf(hv*sg);
        }
    }
    __syncthreads();
    const ushort_t* W1b = W1t + (size_t)chunk*16384;
    #pragma unroll
    for (int it=0; it<8; it++){
        int i = tid*8 + it*2048;
        int row=i>>7, c=i&127;
        *(uint4*)&Ws[row*136+c] = *(const uint4*)&W1b[i];
    }
    __syncthreads();
    f32x4 acc2[8] = {};
    #pragma unroll
    for (int k0=0;k0<128;k0+=32){
        bf16x8 af = *(const bf16x8*)&O1s[(w*16+lr16)*136 + k0 + q*8];
        #pragma unroll
        for (int j=0;j<8;j++){
            bf16x8 bv = *(const bf16x8*)&Ws[(j*16+lr16)*136 + k0 + q*8];
            acc2[j] = __builtin_amdgcn_mfma_f32_16x16x32_bf16(af, bv, acc2[j], 0,0,0);
        }
    }
    float ssq[4] = {0,0,0,0};
    #pragma unroll
    for (int j=0;j<8;j++)
        #pragma unroll
        for (int r=0;r<4;r++) ssq[r] += acc2[j][r]*acc2[j][r];
    #pragma unroll
    for (int r=0;r<4;r++){
        ssq[r] += __shfl_xor(ssq[r], 1, 64);
        ssq[r] += __shfl_xor(ssq[r], 2, 64);
        ssq[r] += __shfl_xor(ssq[r], 4, 64);
        ssq[r] += __shfl_xor(ssq[r], 8, 64);
    }
    int tok0 = n*64 + w*16 + q*4;
    #pragma unroll
    for (int r=0;r<4;r++){
        float rstd = rsqrtf(ssq[r]*(1.0f/128.0f) + EPS_C);
        float gv = gate[((size_t)b*LL + tok0 + r)*4 + h];
        #pragma unroll
        for (int j=0;j<8;j++){
            int d = j*16 + lr16;
            float val = acc2[j][r]*rstd*(gamma[h*128+d]+1.0f)*gv;
            out_pre[((size_t)b*LL + tok0 + r)*DIMM + h*128 + d] = f2bf(val);
        }
    }
}

extern "C" void kernel_launch(void* const* d_in, const int* in_sizes, int n_in,
                              void* d_out, int out_size, void* d_ws, size_t ws_size,
                              hipStream_t stream)
{
    (void)in_sizes; (void)n_in; (void)out_size; (void)ws_size;
    const float* seq    = (const float*)d_in[0];
    const float* sscale = (const float*)d_in[1];
    const float* rscale = (const float*)d_in[2];
    const float* w_q    = (const float*)d_in[3];
    const float* w_kv   = (const float*)d_in[4];
    const float* w_ada  = (const float*)d_in[5];
    const float* w_mom  = (const float*)d_in[6];
    const float* w_dec  = (const float*)d_in[7];
    const float* w0     = (const float*)d_in[8];
    const float* w1     = (const float*)d_in[9];
    const float* gamma  = (const float*)d_in[10];
    const float* w_gate = (const float*)d_in[11];
    const float* w_comb = (const float*)d_in[12];
    const float* empty  = (const float*)d_in[13];
    float* out = (float*)d_out;
    char* wsb = (char*)d_ws;

    ushort_t* bufS  = (ushort_t*)(wsb + 0);          // s
    ushort_t* bufK  = (ushort_t*)(wsb + 8388608);    // keys -> out_pre
    ushort_t* bufV  = (ushort_t*)(wsb + 16777216);   // vals
    ushort_t* bufKT = (ushort_t*)(wsb + 25165824);   // keysT
    ushort_t* bufRC = (ushort_t*)(wsb + 33554432);   // rc (shifted)
    ushort_t* bufQ  = (ushort_t*)(wsb + 41943040);   // q
    ushort_t* G0    = (ushort_t*)(wsb + 50331648);
    ushort_t* G1    = (ushort_t*)(wsb + 67108864);
    ushort_t* wt0T  = (ushort_t*)(wsb + 83886080);
    ushort_t* wt1T  = (ushort_t*)(wsb + 100663296);
    ushort_t* w_kvT   = (ushort_t*)(wsb + 117440512);
    ushort_t* w_qT    = (ushort_t*)(wsb + 118489088);
    ushort_t* w_combT = (ushort_t*)(wsb + 119013376);
    ushort_t* w0T_b   = (ushort_t*)(wsb + 119537664);
    ushort_t* w1T_b   = (ushort_t*)(wsb + 119570432);
    ushort_t* w1row_b = (ushort_t*)(wsb + 119603200);
    float* w0T_f = (float*)(wsb + 119635968);
    float* w1T_f = (float*)(wsb + 119701504);
    float* lrbuf = (float*)(wsb + 119767040);
    float* gtbuf = (float*)(wsb + 119898112);
    float* amraw = (float*)(wsb + 120029184);
    float* dcraw = (float*)(wsb + 120031232);
    ushort_t* wtblS = (ushort_t*)(wsb + 120033280);  // 16 KB [16][512] bf16
    ushort_t* wtblR = (ushort_t*)(wsb + 120049664);  // 16 KB [16][512] bf16

    // 1) norm + weight conversion (independent halves, one dispatch)
    k_init<<<2048 + 4604, 256, 0, stream>>>(seq, sscale, rscale,
        w_kv, w_q, w_comb, w0, w1, empty, w_ada, w_gate, w_mom, w_dec,
        bufS, bufRC, w_kvT, w_qT, w_combT, w0T_b, w1T_b, w1row_b,
        w0T_f, w1T_f, out, wtblS, wtblR);
    // 2) kv GEMM + Q GEMM + projections (all depend only on k_init)
    k_gemms<<<1024, 256, 0, stream>>>(bufS, bufRC, w_kvT, w_qT, wtblS, wtblR,
        bufK, bufKT, bufV, bufQ, lrbuf, gtbuf, amraw, dcraw);
    // 3) fused store pipeline -> g0T(G0), g1T(G1)
    k_fused<<<NCH, 256, 0, stream>>>(bufK, bufV, bufKT, w0T_b, w1T_b, w1row_b,
        lrbuf, G0, G1);
    // 4) both scans -> wt0T / wt1T
    k_scan2<<<256, 256, 0, stream>>>(G0, G1, w0T_f, w1T_f, amraw, dcraw,
        wt0T, wt1T);
    // 5) retrieve -> out_pre (bufK)
    k_retr<<<NCH, 256, 0, stream>>>(bufQ, wt0T, wt1T, gamma, gtbuf, bufK);
    // 6) combine -> d_out (shifted); rows 0..62 filled by k_init
    k_mm<5><<<dim3(4,64), 256, 0, stream>>>(bufK, w_combT, nullptr, nullptr, nullptr,
        out, 512);
}